// Round 1
// baseline (11934.319 us; speedup 1.0000x reference)
//
#include <hip/hip_runtime.h>
#include <math.h>

#define D_MODEL 768
#define D_INNER 1536
#define D_STATE 16
#define DEPTH   12
#define LSEQ    197
#define BATCH   8
#define NPATCH  196
#define ROWS    (BATCH*LSEQ)    // 1576
#define PROWS   (BATCH*NPATCH)  // 1568

__device__ __forceinline__ float siluf(float x) { return x / (1.f + expf(-x)); }

// ---------------- im2col for patch embed ----------------
__global__ void im2col_k(const float* __restrict__ x, float* __restrict__ col) {
  int idx = blockIdx.x * 256 + threadIdx.x;
  if (idx >= PROWS * 768) return;
  int row = idx / 768, i = idx % 768;
  int b = row / NPATCH, p = row % NPATCH;
  int py = p / 14, px = p % 14;
  int ci = i >> 8, rem = i & 255;
  int ky = rem >> 4, kx = rem & 15;
  col[idx] = x[(((size_t)b*3 + ci)*224 + (py*16+ky))*224 + (px*16+kx)];
}

// ---------------- assemble tokens: cls + patches + pos ----------------
__global__ void assemble_k(const float* __restrict__ P, const float* __restrict__ cb,
                           const float* __restrict__ cls, const float* __restrict__ pos,
                           float* __restrict__ t) {
  int bl = blockIdx.x; int b = bl / LSEQ, l = bl % LSEQ;
  for (int c = threadIdx.x; c < 768; c += 256) {
    float v;
    if (l == 0) v = cls[c];
    else        v = P[((size_t)b*NPATCH + (l-1))*768 + c] + cb[c];
    t[(size_t)bl*768 + c] = v + pos[(size_t)l*768 + c];
  }
}

// ---------------- layernorm over 768 ----------------
__global__ void ln_k(const float* __restrict__ x, const float* __restrict__ w,
                     const float* __restrict__ b, float* __restrict__ o) {
  int row = blockIdx.x;
  const float* xr = x + (size_t)row * 768;
  float v[3]; float s = 0.f, ss = 0.f;
  #pragma unroll
  for (int i = 0; i < 3; i++) {
    v[i] = xr[threadIdx.x + i*256]; s += v[i]; ss += v[i]*v[i];
  }
  __shared__ float red[8];
  #pragma unroll
  for (int off = 32; off; off >>= 1) {
    s  += __shfl_down(s, off, 64);
    ss += __shfl_down(ss, off, 64);
  }
  int wv = threadIdx.x >> 6;
  if ((threadIdx.x & 63) == 0) { red[wv] = s; red[wv+4] = ss; }
  __syncthreads();
  if (threadIdx.x == 0) {
    float S = red[0]+red[1]+red[2]+red[3];
    float SS = red[4]+red[5]+red[6]+red[7];
    float m = S * (1.f/768.f);
    float var = SS * (1.f/768.f) - m*m;
    red[0] = m; red[1] = rsqrtf(var + 1e-5f);
  }
  __syncthreads();
  float m = red[0], r = red[1];
  #pragma unroll
  for (int i = 0; i < 3; i++) {
    int c = threadIdx.x + i*256;
    o[(size_t)row*768 + c] = (v[i]-m)*r*w[c] + b[c];
  }
}

// ---------------- generic fp32 GEMM: C[M,N] = A[M,K] @ W[N,K]^T ----------------
// EPI: 0 = none, 1 = +bias then softplus, 2 = +resid (residual add)
template<int EPI>
__global__ void gemm_k(const float* __restrict__ A, const float* __restrict__ W,
                       float* __restrict__ C, const float* __restrict__ bias,
                       const float* __restrict__ resid, int M, int N, int K) {
  __shared__ float As[64][17];
  __shared__ float Ws[64][17];
  int tid = threadIdx.x;
  int m0 = blockIdx.x * 64, n0 = blockIdx.y * 64;
  int tx = tid & 15, ty = tid >> 4;
  float acc[4][4] = {};
  for (int k0 = 0; k0 < K; k0 += 16) {
    #pragma unroll
    for (int i = 0; i < 4; i++) {
      int idx = tid + i*256;
      int r = idx >> 4, c = idx & 15;
      int gm = m0 + r;
      As[r][c] = (gm < M) ? A[(size_t)gm*K + k0 + c] : 0.f;
      Ws[r][c] = W[(size_t)(n0 + r)*K + k0 + c];   // N mult of 64, K mult of 16
    }
    __syncthreads();
    #pragma unroll
    for (int kk = 0; kk < 16; kk++) {
      float av[4], wv[4];
      #pragma unroll
      for (int i = 0; i < 4; i++) av[i] = As[ty*4+i][kk];
      #pragma unroll
      for (int j = 0; j < 4; j++) wv[j] = Ws[tx*4+j][kk];
      #pragma unroll
      for (int i = 0; i < 4; i++)
        #pragma unroll
        for (int j = 0; j < 4; j++)
          acc[i][j] += av[i]*wv[j];
    }
    __syncthreads();
  }
  #pragma unroll
  for (int i = 0; i < 4; i++) {
    int gm = m0 + ty*4 + i;
    if (gm >= M) continue;
    int gn = n0 + tx*4;
    float4 v = make_float4(acc[i][0], acc[i][1], acc[i][2], acc[i][3]);
    if (EPI == 1) {
      v.x += bias[gn]; v.y += bias[gn+1]; v.z += bias[gn+2]; v.w += bias[gn+3];
      v.x = (v.x > 20.f) ? v.x : log1pf(expf(v.x));
      v.y = (v.y > 20.f) ? v.y : log1pf(expf(v.y));
      v.z = (v.z > 20.f) ? v.z : log1pf(expf(v.z));
      v.w = (v.w > 20.f) ? v.w : log1pf(expf(v.w));
    }
    if (EPI == 2) {
      const float4 r4 = *(const float4*)&resid[(size_t)gm*N + gn];
      v.x += r4.x; v.y += r4.y; v.z += r4.z; v.w += r4.w;
    }
    *(float4*)&C[(size_t)gm*N + gn] = v;
  }
}

// ---------------- depthwise causal conv1d + bias + silu ----------------
__global__ void conv_silu_k(const float* __restrict__ xz, const float* __restrict__ cw,
                            const float* __restrict__ cb, float* __restrict__ xc) {
  int idx = blockIdx.x * 256 + threadIdx.x;
  if (idx >= ROWS * D_INNER) return;
  int row = idx / D_INNER, e = idx % D_INNER;
  int b = row / LSEQ, l = row % LSEQ;
  const float* w = cw + (size_t)e * 4;
  float s = cb[e];
  #pragma unroll
  for (int k = 0; k < 4; k++) {
    int lp = l + k - 3;
    if (lp >= 0) s += w[k] * xz[((size_t)(b*LSEQ + lp))*3072 + e];
  }
  xc[idx] = siluf(s);
}

// ---------------- x_proj (only B_ssm half needed): Bs[row,16] = xc[row,:] @ xpw[16,1536]^T
__global__ void xproj_k(const float* __restrict__ xc, const float* __restrict__ xpw,
                        float* __restrict__ Bs) {
  int row = blockIdx.x;
  int n = threadIdx.x & 15, stripe = threadIdx.x >> 4;
  const float* xr = xc + (size_t)row * D_INNER;
  const float* wr = xpw + (size_t)n * D_INNER;
  float s = 0.f;
  int k0 = stripe * 96;
  for (int k = k0; k < k0 + 96; k++) s += xr[k] * wr[k];
  __shared__ float red[16][17];
  red[stripe][n] = s;
  __syncthreads();
  if (threadIdx.x < 16) {
    float t = 0.f;
    #pragma unroll
    for (int i = 0; i < 16; i++) t += red[i][threadIdx.x];
    Bs[(size_t)row*16 + threadIdx.x] = t;
  }
}

// ---------------- selective scan + gate: 16 lanes per (b,d) channel ----------------
__global__ void scan_k(const float* __restrict__ delta, const float* __restrict__ xc,
                       const float* __restrict__ Bs, const float* __restrict__ xz,
                       const float* __restrict__ A_log, const float* __restrict__ Dp,
                       float* __restrict__ y) {
  int grp = threadIdx.x >> 4, n = threadIdx.x & 15;
  int pair = blockIdx.x * 16 + grp;
  int b = pair / D_INNER, d = pair % D_INNER;
  float a = -expf(A_log[(size_t)d*16 + n]);
  float dpd = Dp[d];
  float s = 0.f;
  size_t base = (size_t)b * LSEQ;
  for (int l = 0; l < LSEQ; l++) {
    size_t row = base + l;
    float dv = delta[row*D_INNER + d];
    float xv = xc[row*D_INNER + d];
    float bn = Bs[row*16 + n];
    s = expf(dv * a) * s + dv * xv * bn;
    float part = s * bn;
    part += __shfl_xor(part, 1, 16);
    part += __shfl_xor(part, 2, 16);
    part += __shfl_xor(part, 4, 16);
    part += __shfl_xor(part, 8, 16);
    if (n == 0) {
      float zv = xz[row*3072 + 1536 + d];
      float yv = part + dpd * xv;
      y[row*D_INNER + d] = yv * siluf(zv);
    }
  }
}

extern "C" void kernel_launch(void* const* d_in, const int* in_sizes, int n_in,
                              void* d_out, int out_size, void* d_ws, size_t ws_size,
                              hipStream_t stream) {
  const float* x         = (const float*)d_in[0];
  const float* conv_w    = (const float*)d_in[1];
  const float* conv_b    = (const float*)d_in[2];
  const float* cls_token = (const float*)d_in[3];
  const float* pos_embed = (const float*)d_in[4];
  const float* ln_w      = (const float*)d_in[5];
  const float* ln_b      = (const float*)d_in[6];
  const float* in_proj_w = (const float*)d_in[7];
  const float* conv1d_w  = (const float*)d_in[8];
  const float* conv1d_b  = (const float*)d_in[9];
  const float* x_proj_w  = (const float*)d_in[10];
  const float* dt_proj_w = (const float*)d_in[11];
  const float* dt_proj_b = (const float*)d_in[12];
  const float* A_log     = (const float*)d_in[13];
  const float* D_param   = (const float*)d_in[14];
  const float* out_proj_w= (const float*)d_in[15];
  const float* norm_w    = (const float*)d_in[16];
  const float* norm_b    = (const float*)d_in[17];

  float* ws    = (float*)d_ws;
  float* t     = ws;                      // ROWS*768
  float* xn    = t     + (size_t)ROWS*768;       // ROWS*768
  float* xz    = xn    + (size_t)ROWS*768;       // ROWS*3072
  float* xc    = xz    + (size_t)ROWS*3072;      // ROWS*1536
  float* Bs    = xc    + (size_t)ROWS*1536;      // ROWS*16
  float* delta = Bs    + (size_t)ROWS*16;        // ROWS*1536
  float* y     = delta + (size_t)ROWS*1536;      // ROWS*1536

  // ---- patch embed as GEMM ----
  float* col = xz;  // reuse (1568x768)
  float* P   = xc;  // reuse (1568x768)
  im2col_k<<<(PROWS*768 + 255)/256, 256, 0, stream>>>(x, col);
  gemm_k<0><<<dim3(25, 12), 256, 0, stream>>>(col, conv_w, P, nullptr, nullptr,
                                              PROWS, 768, 768);
  assemble_k<<<ROWS, 256, 0, stream>>>(P, conv_b, cls_token, pos_embed, t);

  for (int i = 0; i < DEPTH; i++) {
    ln_k<<<ROWS, 256, 0, stream>>>(t, ln_w + (size_t)i*768, ln_b + (size_t)i*768, xn);
    gemm_k<0><<<dim3(25, 48), 256, 0, stream>>>(xn, in_proj_w + (size_t)i*3072*768,
                                                xz, nullptr, nullptr, ROWS, 3072, 768);
    conv_silu_k<<<(ROWS*D_INNER + 255)/256, 256, 0, stream>>>(
        xz, conv1d_w + (size_t)i*D_INNER*4, conv1d_b + (size_t)i*D_INNER, xc);
    xproj_k<<<ROWS, 256, 0, stream>>>(xc, x_proj_w + (size_t)i*32*D_INNER + 16*D_INNER, Bs);
    gemm_k<1><<<dim3(25, 24), 256, 0, stream>>>(xc, dt_proj_w + (size_t)i*D_INNER*D_INNER,
                                                delta, dt_proj_b + (size_t)i*D_INNER,
                                                nullptr, ROWS, D_INNER, D_INNER);
    scan_k<<<(BATCH*D_INNER)/16, 256, 0, stream>>>(delta, xc, Bs, xz,
                                                   A_log + (size_t)i*D_INNER*D_STATE,
                                                   D_param + (size_t)i*D_INNER, y);
    gemm_k<2><<<dim3(25, 12), 256, 0, stream>>>(y, out_proj_w + (size_t)i*768*D_INNER,
                                                t, nullptr, t, ROWS, 768, D_INNER);
  }

  ln_k<<<ROWS, 256, 0, stream>>>(t, norm_w, norm_b, (float*)d_out);
}

// Round 2
// 4385.987 us; speedup vs baseline: 2.7210x; 2.7210x over previous
//
#include <hip/hip_runtime.h>
#include <math.h>

#define D_MODEL 768
#define D_INNER 1536
#define D_STATE 16
#define DEPTH   12
#define LSEQ    197
#define BATCH   8
#define NPATCH  196
#define ROWS    (BATCH*LSEQ)    // 1576
#define PROWS   (BATCH*NPATCH)  // 1568
#define MPAD    1664            // 13*128, padded row count for bf16 A operands

typedef __bf16 bf16x8 __attribute__((ext_vector_type(8)));
typedef float  floatx4 __attribute__((ext_vector_type(4)));
typedef __attribute__((address_space(1))) void gvoid;
typedef __attribute__((address_space(3))) void svoid;

__device__ __forceinline__ float siluf(float x) { return x / (1.f + expf(-x)); }

__device__ __forceinline__ void gload_lds16(const void* g, void* s) {
  __builtin_amdgcn_global_load_lds((const gvoid*)g, (svoid*)s, 16, 0, 0);
}

// ---------------- fp32 -> bf16 weight conversion ----------------
__global__ void cvt_k(const float* __restrict__ src, __bf16* __restrict__ dst, int n) {
  int i = (blockIdx.x * 256 + threadIdx.x) * 4;
  if (i >= n) return;
  float4 v = *(const float4*)(src + i);
  union { __bf16 h[4]; unsigned long long u; } p;
  p.h[0] = (__bf16)v.x; p.h[1] = (__bf16)v.y; p.h[2] = (__bf16)v.z; p.h[3] = (__bf16)v.w;
  *(unsigned long long*)(dst + i) = p.u;
}

// convert 3 weight matrices of one layer into one contiguous bf16 buffer
__global__ void cvt3_k(const float* __restrict__ s0, int n0,
                       const float* __restrict__ s1, int n1,
                       const float* __restrict__ s2, int n2,
                       __bf16* __restrict__ dst) {
  int i = (blockIdx.x * 256 + threadIdx.x) * 4;
  const float* s; int off;
  if (i < n0)            { s = s0; off = i; }
  else if (i < n0 + n1)  { s = s1; off = i - n0; }
  else if (i < n0+n1+n2) { s = s2; off = i - n0 - n1; }
  else return;
  float4 v = *(const float4*)(s + off);
  union { __bf16 h[4]; unsigned long long u; } p;
  p.h[0] = (__bf16)v.x; p.h[1] = (__bf16)v.y; p.h[2] = (__bf16)v.z; p.h[3] = (__bf16)v.w;
  *(unsigned long long*)(dst + i) = p.u;
}

// ---------------- im2col for patch embed (bf16 out) ----------------
__global__ void im2col_k(const float* __restrict__ x, __bf16* __restrict__ col) {
  int idx = blockIdx.x * 256 + threadIdx.x;
  if (idx >= PROWS * 768) return;
  int row = idx / 768, i = idx % 768;
  int b = row / NPATCH, p = row % NPATCH;
  int py = p / 14, px = p % 14;
  int ci = i >> 8, rem = i & 255;
  int ky = rem >> 4, kx = rem & 15;
  col[idx] = (__bf16)x[(((size_t)b*3 + ci)*224 + (py*16+ky))*224 + (px*16+kx)];
}

// ---------------- assemble tokens: cls + patches + pos ----------------
__global__ void assemble_k(const float* __restrict__ P, const float* __restrict__ cb,
                           const float* __restrict__ cls, const float* __restrict__ pos,
                           float* __restrict__ t) {
  int bl = blockIdx.x; int b = bl / LSEQ, l = bl % LSEQ;
  for (int c = threadIdx.x; c < 768; c += 256) {
    float v;
    if (l == 0) v = cls[c];
    else        v = P[((size_t)b*NPATCH + (l-1))*768 + c] + cb[c];
    t[(size_t)bl*768 + c] = v + pos[(size_t)l*768 + c];
  }
}

// ---------------- layernorm over 768, templated output dtype ----------------
template<typename T>
__global__ void ln_k(const float* __restrict__ x, const float* __restrict__ w,
                     const float* __restrict__ b, T* __restrict__ o) {
  int row = blockIdx.x;
  const float* xr = x + (size_t)row * 768;
  float v[3]; float s = 0.f, ss = 0.f;
  #pragma unroll
  for (int i = 0; i < 3; i++) {
    v[i] = xr[threadIdx.x + i*256]; s += v[i]; ss += v[i]*v[i];
  }
  __shared__ float red[8];
  #pragma unroll
  for (int off = 32; off; off >>= 1) {
    s  += __shfl_down(s, off, 64);
    ss += __shfl_down(ss, off, 64);
  }
  int wv = threadIdx.x >> 6;
  if ((threadIdx.x & 63) == 0) { red[wv] = s; red[wv+4] = ss; }
  __syncthreads();
  if (threadIdx.x == 0) {
    float S = red[0]+red[1]+red[2]+red[3];
    float SS = red[4]+red[5]+red[6]+red[7];
    float m = S * (1.f/768.f);
    float var = SS * (1.f/768.f) - m*m;
    red[0] = m; red[1] = rsqrtf(var + 1e-5f);
  }
  __syncthreads();
  float m = red[0], r = red[1];
  #pragma unroll
  for (int i = 0; i < 3; i++) {
    int c = threadIdx.x + i*256;
    o[(size_t)row*768 + c] = (T)((v[i]-m)*r*w[c] + b[c]);
  }
}

// ---------------- bf16 MFMA GEMM: C[M,N] = A[M,K] @ W[N,K]^T (fp32 out) ----------------
// m97 structure: 128x128 tile, BK=32, 4 waves (2x2), each wave 64x64 via 4x4 mfma_16x16x32.
// A must be padded to >= gridDim.x*128 rows. N % 128 == 0, K % 32 == 0.
// EPI: 0 = none, 1 = +bias then softplus, 2 = +resid
template<int EPI>
__global__ __launch_bounds__(256) void mgemm_k(const __bf16* __restrict__ A,
    const __bf16* __restrict__ W, float* __restrict__ C,
    const float* __restrict__ bias, const float* __restrict__ resid,
    int M, int N, int K) {
  __shared__ __bf16 sA[128*32];
  __shared__ __bf16 sB[128*32];
  const int tid = threadIdx.x, wave = tid >> 6, lane = tid & 63;
  const int m0 = blockIdx.x * 128, n0 = blockIdx.y * 128;
  const int wm = (wave & 1) * 64, wn = (wave >> 1) * 64;

  floatx4 acc[4][4] = {};

  // staging: each wave stages 16 rows per instruction (64 lanes x 16B = 16 rows of 64B)
  const int srow = wave * 16 + (lane >> 2);   // 0..63
  const int scol = (lane & 3) * 8;            // bf16 element offset in row
  const __bf16* gA0 = A + (size_t)(m0 + srow) * K + scol;
  const __bf16* gA1 = A + (size_t)(m0 + 64 + srow) * K + scol;
  const __bf16* gB0 = W + (size_t)(n0 + srow) * K + scol;
  const __bf16* gB1 = W + (size_t)(n0 + 64 + srow) * K + scol;
  __bf16* lA0 = sA + srow * 32 + scol;        // byte off = wave*1024 + lane*16
  __bf16* lA1 = lA0 + 64 * 32;
  __bf16* lB0 = sB + srow * 32 + scol;
  __bf16* lB1 = lB0 + 64 * 32;

  // fragment read pointers
  const __bf16* pA = sA + (wm + (lane & 15)) * 32 + (lane >> 4) * 8;
  const __bf16* pB = sB + (wn + (lane & 15)) * 32 + (lane >> 4) * 8;

  for (int k0 = 0; k0 < K; k0 += 32) {
    gload_lds16(gA0 + k0, lA0);
    gload_lds16(gA1 + k0, lA1);
    gload_lds16(gB0 + k0, lB0);
    gload_lds16(gB1 + k0, lB1);
    __syncthreads();
    bf16x8 af[4], bfr[4];
    #pragma unroll
    for (int i = 0; i < 4; i++) af[i]  = *(const bf16x8*)(pA + i * 16 * 32);
    #pragma unroll
    for (int j = 0; j < 4; j++) bfr[j] = *(const bf16x8*)(pB + j * 16 * 32);
    #pragma unroll
    for (int i = 0; i < 4; i++)
      #pragma unroll
      for (int j = 0; j < 4; j++)
        acc[i][j] = __builtin_amdgcn_mfma_f32_16x16x32_bf16(af[i], bfr[j], acc[i][j], 0, 0, 0);
    __syncthreads();
  }

  // epilogue: C/D layout col=lane&15, row=(lane>>4)*4+reg
  const int en = n0 + wn + (lane & 15);
  const int em = m0 + wm + (lane >> 4) * 4;
  #pragma unroll
  for (int i = 0; i < 4; i++) {
    #pragma unroll
    for (int r = 0; r < 4; r++) {
      int m = em + i * 16 + r;
      if (m >= M) continue;
      #pragma unroll
      for (int j = 0; j < 4; j++) {
        int n = en + j * 16;
        float v = acc[i][j][r];
        if (EPI == 1) { v += bias[n]; v = (v > 20.f) ? v : log1pf(expf(v)); }
        if (EPI == 2) { v += resid[(size_t)m * N + n]; }
        C[(size_t)m * N + n] = v;
      }
    }
  }
}

// ---------------- depthwise causal conv1d + bias + silu (fp32 + bf16 out) ----------------
__global__ void conv_silu_k(const float* __restrict__ xz, const float* __restrict__ cw,
                            const float* __restrict__ cb, float* __restrict__ xc,
                            __bf16* __restrict__ xcb) {
  int idx = blockIdx.x * 256 + threadIdx.x;
  if (idx >= ROWS * D_INNER) return;
  int row = idx / D_INNER, e = idx % D_INNER;
  int b = row / LSEQ, l = row % LSEQ;
  const float* w = cw + (size_t)e * 4;
  float s = cb[e];
  #pragma unroll
  for (int k = 0; k < 4; k++) {
    int lp = l + k - 3;
    if (lp >= 0) s += w[k] * xz[((size_t)(b*LSEQ + lp))*3072 + e];
  }
  float r = siluf(s);
  xc[idx] = r;
  xcb[idx] = (__bf16)r;
}

// ---------------- x_proj (only B_ssm half needed) ----------------
__global__ void xproj_k(const float* __restrict__ xc, const float* __restrict__ xpw,
                        float* __restrict__ Bs) {
  int row = blockIdx.x;
  int n = threadIdx.x & 15, stripe = threadIdx.x >> 4;
  const float* xr = xc + (size_t)row * D_INNER;
  const float* wr = xpw + (size_t)n * D_INNER;
  float s = 0.f;
  int k0 = stripe * 96;
  for (int k = k0; k < k0 + 96; k++) s += xr[k] * wr[k];
  __shared__ float red[16][17];
  red[stripe][n] = s;
  __syncthreads();
  if (threadIdx.x < 16) {
    float t = 0.f;
    #pragma unroll
    for (int i = 0; i < 16; i++) t += red[i][threadIdx.x];
    Bs[(size_t)row*16 + threadIdx.x] = t;
  }
}

// ---------------- selective scan + gate: 16 lanes per (b,d) channel, bf16 y ----------------
__global__ void scan_k(const float* __restrict__ delta, const float* __restrict__ xc,
                       const float* __restrict__ Bs, const float* __restrict__ xz,
                       const float* __restrict__ A_log, const float* __restrict__ Dp,
                       __bf16* __restrict__ y) {
  int grp = threadIdx.x >> 4, n = threadIdx.x & 15;
  int pair = blockIdx.x * 16 + grp;
  int b = pair / D_INNER, d = pair % D_INNER;
  float a = -expf(A_log[(size_t)d*16 + n]);
  float dpd = Dp[d];
  float s = 0.f;
  size_t base = (size_t)b * LSEQ;
  for (int l = 0; l < LSEQ; l++) {
    size_t row = base + l;
    float dv = delta[row*D_INNER + d];
    float xv = xc[row*D_INNER + d];
    float bn = Bs[row*16 + n];
    s = expf(dv * a) * s + dv * xv * bn;
    float part = s * bn;
    part += __shfl_xor(part, 1, 16);
    part += __shfl_xor(part, 2, 16);
    part += __shfl_xor(part, 4, 16);
    part += __shfl_xor(part, 8, 16);
    if (n == 0) {
      float zv = xz[row*3072 + 1536 + d];
      float yv = part + dpd * xv;
      y[row*D_INNER + d] = (__bf16)(yv * siluf(zv));
    }
  }
}

extern "C" void kernel_launch(void* const* d_in, const int* in_sizes, int n_in,
                              void* d_out, int out_size, void* d_ws, size_t ws_size,
                              hipStream_t stream) {
  const float* x         = (const float*)d_in[0];
  const float* conv_w    = (const float*)d_in[1];
  const float* conv_b    = (const float*)d_in[2];
  const float* cls_token = (const float*)d_in[3];
  const float* pos_embed = (const float*)d_in[4];
  const float* ln_w      = (const float*)d_in[5];
  const float* ln_b      = (const float*)d_in[6];
  const float* in_proj_w = (const float*)d_in[7];
  const float* conv1d_w  = (const float*)d_in[8];
  const float* conv1d_b  = (const float*)d_in[9];
  const float* x_proj_w  = (const float*)d_in[10];
  const float* dt_proj_w = (const float*)d_in[11];
  const float* dt_proj_b = (const float*)d_in[12];
  const float* A_log     = (const float*)d_in[13];
  const float* D_param   = (const float*)d_in[14];
  const float* out_proj_w= (const float*)d_in[15];
  const float* norm_w    = (const float*)d_in[16];
  const float* norm_b    = (const float*)d_in[17];

  const int N_IN  = 2*D_INNER*D_MODEL;   // 2359296
  const int N_DT  = D_INNER*D_INNER;     // 2359296
  const int N_OUT = D_MODEL*D_INNER;     // 1179648

  char* wsb = (char*)d_ws;
  size_t off = 0;
  float* t     = (float*)(wsb + off); off += (size_t)ROWS*768*4;
  float* xz    = (float*)(wsb + off); off += (size_t)ROWS*3072*4;
  float* xc    = (float*)(wsb + off); off += (size_t)ROWS*1536*4;
  float* delta = (float*)(wsb + off); off += (size_t)ROWS*1536*4;
  float* Bs    = (float*)(wsb + off); off += (size_t)ROWS*16*4;
  __bf16* xn_b = (__bf16*)(wsb + off); off += (size_t)MPAD*768*2;
  __bf16* xc_b = (__bf16*)(wsb + off); off += (size_t)MPAD*1536*2;
  __bf16* y_b  = (__bf16*)(wsb + off); off += (size_t)MPAD*1536*2;
  __bf16* col_b= (__bf16*)(wsb + off); off += (size_t)MPAD*768*2;
  __bf16* cw_b = (__bf16*)(wsb + off); off += (size_t)768*768*2;
  __bf16* wbuf = (__bf16*)(wsb + off); off += (size_t)(N_IN+N_DT+N_OUT)*2;

  // ---- patch embed as bf16 MFMA GEMM ----
  float* P = xz;  // reuse (1568x768), free at this point
  im2col_k<<<(PROWS*768 + 255)/256, 256, 0, stream>>>(x, col_b);
  cvt_k<<<(768*768/4 + 255)/256, 256, 0, stream>>>(conv_w, cw_b, 768*768);
  mgemm_k<0><<<dim3(13, 6), 256, 0, stream>>>(col_b, cw_b, P, nullptr, nullptr,
                                              PROWS, 768, 768);
  assemble_k<<<ROWS, 256, 0, stream>>>(P, conv_b, cls_token, pos_embed, t);

  for (int i = 0; i < DEPTH; i++) {
    cvt3_k<<<(N_IN+N_DT+N_OUT)/4/256, 256, 0, stream>>>(
        in_proj_w + (size_t)i*N_IN, N_IN,
        dt_proj_w + (size_t)i*N_DT, N_DT,
        out_proj_w + (size_t)i*N_OUT, N_OUT, wbuf);
    ln_k<__bf16><<<ROWS, 256, 0, stream>>>(t, ln_w + (size_t)i*768, ln_b + (size_t)i*768, xn_b);
    mgemm_k<0><<<dim3(13, 24), 256, 0, stream>>>(xn_b, wbuf, xz, nullptr, nullptr,
                                                 ROWS, 3072, 768);
    conv_silu_k<<<(ROWS*D_INNER + 255)/256, 256, 0, stream>>>(
        xz, conv1d_w + (size_t)i*D_INNER*4, conv1d_b + (size_t)i*D_INNER, xc, xc_b);
    xproj_k<<<ROWS, 256, 0, stream>>>(xc, x_proj_w + (size_t)i*32*D_INNER + 16*D_INNER, Bs);
    mgemm_k<1><<<dim3(13, 12), 256, 0, stream>>>(xc_b, wbuf + N_IN, delta,
                                                 dt_proj_b + (size_t)i*D_INNER, nullptr,
                                                 ROWS, 1536, 1536);
    scan_k<<<(BATCH*D_INNER)/16, 256, 0, stream>>>(delta, xc, Bs, xz,
                                                   A_log + (size_t)i*D_INNER*D_STATE,
                                                   D_param + (size_t)i*D_INNER, y_b);
    mgemm_k<2><<<dim3(13, 6), 256, 0, stream>>>(y_b, wbuf + N_IN + N_DT, t,
                                                nullptr, t, ROWS, 768, D_INNER);
  }

  ln_k<float><<<ROWS, 256, 0, stream>>>(t, norm_w, norm_b, (float*)d_out);
}

// Round 3
// 3198.033 us; speedup vs baseline: 3.7318x; 1.3715x over previous
//
#include <hip/hip_runtime.h>
#include <math.h>

#define D_MODEL 768
#define D_INNER 1536
#define D_STATE 16
#define DEPTH   12
#define LSEQ    197
#define BATCH   8
#define NPATCH  196
#define ROWS    (BATCH*LSEQ)    // 1576
#define PROWS   (BATCH*NPATCH)  // 1568
#define MPAD    1664            // 13*128, padded row count for bf16 A operands
#define LP      208             // padded time axis for transposed scan arrays

typedef __bf16 bf16x8 __attribute__((ext_vector_type(8)));
typedef float  floatx4 __attribute__((ext_vector_type(4)));
typedef __attribute__((address_space(1))) void gvoid;
typedef __attribute__((address_space(3))) void svoid;

__device__ __forceinline__ float siluf(float x) { return x / (1.f + __expf(-x)); }

__device__ __forceinline__ void gload_lds16(const void* g, void* s) {
  __builtin_amdgcn_global_load_lds((const gvoid*)g, (svoid*)s, 16, 0, 0);
}

// ---------------- fp32 -> bf16 weight conversion ----------------
__global__ void cvt_k(const float* __restrict__ src, __bf16* __restrict__ dst, int n) {
  int i = (blockIdx.x * 256 + threadIdx.x) * 4;
  if (i >= n) return;
  float4 v = *(const float4*)(src + i);
  union { __bf16 h[4]; unsigned long long u; } p;
  p.h[0] = (__bf16)v.x; p.h[1] = (__bf16)v.y; p.h[2] = (__bf16)v.z; p.h[3] = (__bf16)v.w;
  *(unsigned long long*)(dst + i) = p.u;
}

__global__ void cvt3_k(const float* __restrict__ s0, int n0,
                       const float* __restrict__ s1, int n1,
                       const float* __restrict__ s2, int n2,
                       __bf16* __restrict__ dst) {
  int i = (blockIdx.x * 256 + threadIdx.x) * 4;
  const float* s; int off;
  if (i < n0)            { s = s0; off = i; }
  else if (i < n0 + n1)  { s = s1; off = i - n0; }
  else if (i < n0+n1+n2) { s = s2; off = i - n0 - n1; }
  else return;
  float4 v = *(const float4*)(s + off);
  union { __bf16 h[4]; unsigned long long u; } p;
  p.h[0] = (__bf16)v.x; p.h[1] = (__bf16)v.y; p.h[2] = (__bf16)v.z; p.h[3] = (__bf16)v.w;
  *(unsigned long long*)(dst + i) = p.u;
}

// ---------------- im2col for patch embed (bf16 out) ----------------
__global__ void im2col_k(const float* __restrict__ x, __bf16* __restrict__ col) {
  int idx = blockIdx.x * 256 + threadIdx.x;
  if (idx >= PROWS * 768) return;
  int row = idx / 768, i = idx % 768;
  int b = row / NPATCH, p = row % NPATCH;
  int py = p / 14, px = p % 14;
  int ci = i >> 8, rem = i & 255;
  int ky = rem >> 4, kx = rem & 15;
  col[idx] = (__bf16)x[(((size_t)b*3 + ci)*224 + (py*16+ky))*224 + (px*16+kx)];
}

// ---------------- assemble tokens: cls + patches + pos ----------------
__global__ void assemble_k(const float* __restrict__ P, const float* __restrict__ cb,
                           const float* __restrict__ cls, const float* __restrict__ pos,
                           float* __restrict__ t) {
  int bl = blockIdx.x; int b = bl / LSEQ, l = bl % LSEQ;
  for (int c = threadIdx.x; c < 768; c += 256) {
    float v;
    if (l == 0) v = cls[c];
    else        v = P[((size_t)b*NPATCH + (l-1))*768 + c] + cb[c];
    t[(size_t)bl*768 + c] = v + pos[(size_t)l*768 + c];
  }
}

// ---------------- layernorm over 768, templated output dtype ----------------
template<typename T>
__global__ void ln_k(const float* __restrict__ x, const float* __restrict__ w,
                     const float* __restrict__ b, T* __restrict__ o) {
  int row = blockIdx.x;
  const float* xr = x + (size_t)row * 768;
  float v[3]; float s = 0.f, ss = 0.f;
  #pragma unroll
  for (int i = 0; i < 3; i++) {
    v[i] = xr[threadIdx.x + i*256]; s += v[i]; ss += v[i]*v[i];
  }
  __shared__ float red[8];
  #pragma unroll
  for (int off = 32; off; off >>= 1) {
    s  += __shfl_down(s, off, 64);
    ss += __shfl_down(ss, off, 64);
  }
  int wv = threadIdx.x >> 6;
  if ((threadIdx.x & 63) == 0) { red[wv] = s; red[wv+4] = ss; }
  __syncthreads();
  if (threadIdx.x == 0) {
    float S = red[0]+red[1]+red[2]+red[3];
    float SS = red[4]+red[5]+red[6]+red[7];
    float m = S * (1.f/768.f);
    float var = SS * (1.f/768.f) - m*m;
    red[0] = m; red[1] = rsqrtf(var + 1e-5f);
  }
  __syncthreads();
  float m = red[0], r = red[1];
  #pragma unroll
  for (int i = 0; i < 3; i++) {
    int c = threadIdx.x + i*256;
    o[(size_t)row*768 + c] = (T)((v[i]-m)*r*w[c] + b[c]);
  }
}

// ---------------- bf16 MFMA GEMM: C[M,N] = A[M,K] @ W[N,K]^T ----------------
// EPI: 0 = plain fp32 C, 2 = +resid, 3 = raw transposed write to dvT[ch*LP+l]
template<int EPI>
__global__ __launch_bounds__(256) void mgemm_k(const __bf16* __restrict__ A,
    const __bf16* __restrict__ W, float* __restrict__ C,
    const float* __restrict__ resid, int M, int N, int K) {
  __shared__ __bf16 sA[128*32];
  __shared__ __bf16 sB[128*32];
  const int tid = threadIdx.x, wave = tid >> 6, lane = tid & 63;
  const int m0 = blockIdx.x * 128, n0 = blockIdx.y * 128;
  const int wm = (wave & 1) * 64, wn = (wave >> 1) * 64;

  floatx4 acc[4][4] = {};

  const int srow = wave * 16 + (lane >> 2);
  const int scol = (lane & 3) * 8;
  const __bf16* gA0 = A + (size_t)(m0 + srow) * K + scol;
  const __bf16* gA1 = A + (size_t)(m0 + 64 + srow) * K + scol;
  const __bf16* gB0 = W + (size_t)(n0 + srow) * K + scol;
  const __bf16* gB1 = W + (size_t)(n0 + 64 + srow) * K + scol;
  __bf16* lA0 = sA + srow * 32 + scol;
  __bf16* lA1 = lA0 + 64 * 32;
  __bf16* lB0 = sB + srow * 32 + scol;
  __bf16* lB1 = lB0 + 64 * 32;

  const __bf16* pA = sA + (wm + (lane & 15)) * 32 + (lane >> 4) * 8;
  const __bf16* pB = sB + (wn + (lane & 15)) * 32 + (lane >> 4) * 8;

  for (int k0 = 0; k0 < K; k0 += 32) {
    gload_lds16(gA0 + k0, lA0);
    gload_lds16(gA1 + k0, lA1);
    gload_lds16(gB0 + k0, lB0);
    gload_lds16(gB1 + k0, lB1);
    __syncthreads();
    bf16x8 af[4], bfr[4];
    #pragma unroll
    for (int i = 0; i < 4; i++) af[i]  = *(const bf16x8*)(pA + i * 16 * 32);
    #pragma unroll
    for (int j = 0; j < 4; j++) bfr[j] = *(const bf16x8*)(pB + j * 16 * 32);
    #pragma unroll
    for (int i = 0; i < 4; i++)
      #pragma unroll
      for (int j = 0; j < 4; j++)
        acc[i][j] = __builtin_amdgcn_mfma_f32_16x16x32_bf16(af[i], bfr[j], acc[i][j], 0, 0, 0);
    __syncthreads();
  }

  const int en = n0 + wn + (lane & 15);
  const int em = m0 + wm + (lane >> 4) * 4;
  if (EPI == 3) {
    // transposed store: C here is dvT[(b*D_INNER + n)*LP + l], raw pre-softplus
    #pragma unroll
    for (int i = 0; i < 4; i++) {
      int mr = em + i * 16;
      int b0 = mr / LSEQ, l0 = mr - b0 * LSEQ;
      bool fast = (l0 + 3 < LSEQ) && (mr + 3 < M);
      #pragma unroll
      for (int j = 0; j < 4; j++) {
        int d = en + j * 16;
        float* p = C + ((size_t)b0 * D_INNER + d) * LP + l0;
        if (fast) {
          p[0] = acc[i][j][0]; p[1] = acc[i][j][1];
          p[2] = acc[i][j][2]; p[3] = acc[i][j][3];
        } else {
          #pragma unroll
          for (int r = 0; r < 4; r++) {
            int m = mr + r;
            if (m >= M) continue;
            int bb = m / LSEQ, ll = m - bb * LSEQ;
            C[((size_t)bb * D_INNER + d) * LP + ll] = acc[i][j][r];
          }
        }
      }
    }
  } else {
    #pragma unroll
    for (int i = 0; i < 4; i++) {
      #pragma unroll
      for (int r = 0; r < 4; r++) {
        int m = em + i * 16 + r;
        if (m >= M) continue;
        #pragma unroll
        for (int j = 0; j < 4; j++) {
          int n = en + j * 16;
          float v = acc[i][j][r];
          if (EPI == 2) v += resid[(size_t)m * N + n];
          C[(size_t)m * N + n] = v;
        }
      }
    }
  }
}

// ---------------- fused depthwise conv1d + silu + gate-prep (transposed outputs) ----
// grid (8, 6, 4), block 256. Emits xc_b[row][d] (bf16), xvT/gmT/gaT [ch][l] (fp32).
__global__ __launch_bounds__(256) void convf_k(const float* __restrict__ xz,
    const float* __restrict__ cw, const float* __restrict__ cb,
    const float* __restrict__ Dp, __bf16* __restrict__ xc_b,
    float* __restrict__ xvT, float* __restrict__ gmT, float* __restrict__ gaT) {
  const int b = blockIdx.x, dc = blockIdx.y, lc = blockIdx.z * 52;
  const int d = dc * 256 + threadIdx.x;
  const int lend = min(lc + 52, LSEQ);
  const float* w = cw + (size_t)d * 4;
  const float w0 = w[0], w1 = w[1], w2 = w[2], w3 = w[3];
  const float bias = cb[d], dp = Dp[d];
  float xm3 = 0.f, xm2 = 0.f, xm1 = 0.f;
  const size_t rowbase = ((size_t)b * LSEQ) * 3072 + d;
  if (lc >= 3) {
    xm3 = xz[rowbase + (size_t)(lc-3)*3072];
    xm2 = xz[rowbase + (size_t)(lc-2)*3072];
    xm1 = xz[rowbase + (size_t)(lc-1)*3072];
  }
  const size_t ch = (size_t)b * D_INNER + d;
  float* pxv = xvT + ch * LP;
  float* pgm = gmT + ch * LP;
  float* pga = gaT + ch * LP;

  int l = lc;
  for (; l + 3 < lend; l += 4) {
    float4 bxv, bgm, bga;
    #pragma unroll
    for (int q = 0; q < 4; q++) {
      int lq = l + q;
      float x0 = xz[rowbase + (size_t)lq*3072];
      float zc = xz[rowbase + (size_t)lq*3072 + 1536];
      float c = w0*xm3 + w1*xm2 + w2*xm1 + w3*x0 + bias;
      xm3 = xm2; xm2 = xm1; xm1 = x0;
      float xc = siluf(c);
      float gm = siluf(zc);
      (&bxv.x)[q] = xc; (&bgm.x)[q] = gm; (&bga.x)[q] = dp*xc*gm;
      xc_b[((size_t)b*LSEQ + lq)*D_INNER + d] = (__bf16)xc;
    }
    *(float4*)(pxv + l) = bxv;
    *(float4*)(pgm + l) = bgm;
    *(float4*)(pga + l) = bga;
  }
  for (; l < lend; l++) {
    float x0 = xz[rowbase + (size_t)l*3072];
    float zc = xz[rowbase + (size_t)l*3072 + 1536];
    float c = w0*xm3 + w1*xm2 + w2*xm1 + w3*x0 + bias;
    xm3 = xm2; xm2 = xm1; xm1 = x0;
    float xc = siluf(c);
    float gm = siluf(zc);
    xc_b[((size_t)b*LSEQ + l)*D_INNER + d] = (__bf16)xc;
    pxv[l] = xc; pgm[l] = gm; pga[l] = dp*xc*gm;
  }
}

// ---------------- x_proj (only B_ssm half needed), bf16 activations ----------------
__global__ void xproj_k(const __bf16* __restrict__ xc, const float* __restrict__ xpw,
                        float* __restrict__ Bs) {
  int row = blockIdx.x;
  int n = threadIdx.x & 15, stripe = threadIdx.x >> 4;
  const __bf16* xr = xc + (size_t)row * D_INNER;
  const float* wr = xpw + (size_t)n * D_INNER;
  float s = 0.f;
  int k0 = stripe * 96;
  for (int k = k0; k < k0 + 96; k++) s += (float)xr[k] * wr[k];
  __shared__ float red[16][17];
  red[stripe][n] = s;
  __syncthreads();
  if (threadIdx.x < 16) {
    float t = 0.f;
    #pragma unroll
    for (int i = 0; i < 16; i++) t += red[i][threadIdx.x];
    Bs[(size_t)row*16 + threadIdx.x] = t;
  }
}

// ---------------- selective scan, chunked-register version ----------------
// 16 lanes per channel; 13 chunks of 16 timesteps; softplus+bias applied here.
__global__ __launch_bounds__(256) void scan2_k(const float* __restrict__ dvT,
    const float* __restrict__ xvT, const float* __restrict__ gmT,
    const float* __restrict__ gaT, const float* __restrict__ Bs,
    const float* __restrict__ A_log, const float* __restrict__ dt_b,
    __bf16* __restrict__ y) {
  const int grp = threadIdx.x >> 4, n = threadIdx.x & 15;
  const int ch = blockIdx.x * 16 + grp;
  const int b = ch / D_INNER, d = ch - b * D_INNER;
  const float a = -__expf(A_log[(size_t)d * 16 + n]);
  const float bias = dt_b[d];
  const size_t base = (size_t)ch * LP;
  const size_t brow = (size_t)b * LSEQ;
  float s = 0.f;
  for (int l0 = 0; l0 < LSEQ; l0 += 16) {
    const int li = l0 + n;
    float v  = dvT[base + li] + bias;
    float xv = xvT[base + li];
    float gm = gmT[base + li];
    float ga = gaT[base + li];
    float dv = (v > 20.f) ? v : log1pf(__expf(v));
    float u  = dv * xv;
    #pragma unroll
    for (int j = 0; j < 16; j++) {
      float bdv = __shfl(dv, j, 16);
      float bu  = __shfl(u,  j, 16);
      float bn  = Bs[(brow + l0 + j) * 16 + n];
      s = __expf(bdv * a) * s + bu * bn;
      float part = s * bn;
      part += __shfl_xor(part, 1, 16);
      part += __shfl_xor(part, 2, 16);
      part += __shfl_xor(part, 4, 16);
      part += __shfl_xor(part, 8, 16);
      if (n == j && l0 + j < LSEQ) {
        y[(brow + l0 + j) * D_INNER + d] = (__bf16)(part * gm + ga);
      }
    }
  }
}

extern "C" void kernel_launch(void* const* d_in, const int* in_sizes, int n_in,
                              void* d_out, int out_size, void* d_ws, size_t ws_size,
                              hipStream_t stream) {
  const float* x         = (const float*)d_in[0];
  const float* conv_w    = (const float*)d_in[1];
  const float* conv_b    = (const float*)d_in[2];
  const float* cls_token = (const float*)d_in[3];
  const float* pos_embed = (const float*)d_in[4];
  const float* ln_w      = (const float*)d_in[5];
  const float* ln_b      = (const float*)d_in[6];
  const float* in_proj_w = (const float*)d_in[7];
  const float* conv1d_w  = (const float*)d_in[8];
  const float* conv1d_b  = (const float*)d_in[9];
  const float* x_proj_w  = (const float*)d_in[10];
  const float* dt_proj_w = (const float*)d_in[11];
  const float* dt_proj_b = (const float*)d_in[12];
  const float* A_log     = (const float*)d_in[13];
  const float* D_param   = (const float*)d_in[14];
  const float* out_proj_w= (const float*)d_in[15];
  const float* norm_w    = (const float*)d_in[16];
  const float* norm_b    = (const float*)d_in[17];

  const int N_IN  = 2*D_INNER*D_MODEL;
  const int N_DT  = D_INNER*D_INNER;
  const int N_OUT = D_MODEL*D_INNER;
  const size_t TSZ = (size_t)BATCH * D_INNER * LP * 4;  // transposed array bytes

  char* wsb = (char*)d_ws;
  size_t off = 0;
  float* t     = (float*)(wsb + off); off += (size_t)ROWS*768*4;
  float* xz    = (float*)(wsb + off); off += (size_t)ROWS*3072*4;
  float* Bs    = (float*)(wsb + off); off += (size_t)ROWS*16*4 + 1024;  // pad: scan tail over-reads
  float* dvT   = (float*)(wsb + off); off += TSZ;
  float* xvT   = (float*)(wsb + off); off += TSZ;
  float* gmT   = (float*)(wsb + off); off += TSZ;
  float* gaT   = (float*)(wsb + off); off += TSZ;
  __bf16* xn_b = (__bf16*)(wsb + off); off += (size_t)MPAD*768*2;
  __bf16* xc_b = (__bf16*)(wsb + off); off += (size_t)MPAD*1536*2;
  __bf16* y_b  = (__bf16*)(wsb + off); off += (size_t)MPAD*1536*2;
  __bf16* col_b= (__bf16*)(wsb + off); off += (size_t)MPAD*768*2;
  __bf16* cw_b = (__bf16*)(wsb + off); off += (size_t)768*768*2;
  __bf16* wbuf = (__bf16*)(wsb + off); off += (size_t)(N_IN+N_DT+N_OUT)*2;

  // ---- patch embed as bf16 MFMA GEMM ----
  float* P = xz;  // reuse
  im2col_k<<<(PROWS*768 + 255)/256, 256, 0, stream>>>(x, col_b);
  cvt_k<<<(768*768/4 + 255)/256, 256, 0, stream>>>(conv_w, cw_b, 768*768);
  mgemm_k<0><<<dim3(13, 6), 256, 0, stream>>>(col_b, cw_b, P, nullptr, PROWS, 768, 768);
  assemble_k<<<ROWS, 256, 0, stream>>>(P, conv_b, cls_token, pos_embed, t);

  for (int i = 0; i < DEPTH; i++) {
    cvt3_k<<<(N_IN+N_DT+N_OUT)/4/256, 256, 0, stream>>>(
        in_proj_w + (size_t)i*N_IN, N_IN,
        dt_proj_w + (size_t)i*N_DT, N_DT,
        out_proj_w + (size_t)i*N_OUT, N_OUT, wbuf);
    ln_k<__bf16><<<ROWS, 256, 0, stream>>>(t, ln_w + (size_t)i*768, ln_b + (size_t)i*768, xn_b);
    mgemm_k<0><<<dim3(13, 24), 256, 0, stream>>>(xn_b, wbuf, xz, nullptr, ROWS, 3072, 768);
    convf_k<<<dim3(8, 6, 4), 256, 0, stream>>>(xz, conv1d_w + (size_t)i*D_INNER*4,
        conv1d_b + (size_t)i*D_INNER, D_param + (size_t)i*D_INNER,
        xc_b, xvT, gmT, gaT);
    xproj_k<<<ROWS, 256, 0, stream>>>(xc_b, x_proj_w + (size_t)i*32*D_INNER + 16*D_INNER, Bs);
    mgemm_k<3><<<dim3(13, 12), 256, 0, stream>>>(xc_b, wbuf + N_IN, dvT, nullptr,
                                                 ROWS, 1536, 1536);
    scan2_k<<<(BATCH*D_INNER)/16, 256, 0, stream>>>(dvT, xvT, gmT, gaT, Bs,
        A_log + (size_t)i*D_INNER*D_STATE, dt_proj_b + (size_t)i*D_INNER, y_b);
    mgemm_k<2><<<dim3(13, 6), 256, 0, stream>>>(y_b, wbuf + N_IN + N_DT, t, t,
                                                ROWS, 768, D_INNER);
  }

  ln_k<float><<<ROWS, 256, 0, stream>>>(t, norm_w, norm_b, (float*)d_out);
}

// Round 4
// 2672.449 us; speedup vs baseline: 4.4657x; 1.1967x over previous
//
#include <hip/hip_runtime.h>
#include <math.h>

#define D_MODEL 768
#define D_INNER 1536
#define D_STATE 16
#define DEPTH   12
#define LSEQ    197
#define BATCH   8
#define NPATCH  196
#define ROWS    (BATCH*LSEQ)    // 1576
#define PROWS   (BATCH*NPATCH)  // 1568
#define MPAD    1664            // 13*128 = 26*64, padded row count for bf16 A operands
#define LP      208             // padded time axis for transposed scan arrays (13*16)

typedef __bf16 bf16x8 __attribute__((ext_vector_type(8)));
typedef float  floatx4 __attribute__((ext_vector_type(4)));
typedef __attribute__((address_space(1))) void gvoid;
typedef __attribute__((address_space(3))) void svoid;

__device__ __forceinline__ float siluf(float x) { return x / (1.f + __expf(-x)); }

__device__ __forceinline__ void gload_lds16(const void* g, void* s) {
  __builtin_amdgcn_global_load_lds((const gvoid*)g, (svoid*)s, 16, 0, 0);
}

// DPP cross-lane add within 16-lane rows; CTRL: 0xB1=xor1, 0x4E=xor2,
// 0x141=ROW_HALF_MIRROR (xor7), 0x140=ROW_MIRROR (xor15). VALU pipe, no DS.
template<int CTRL>
__device__ __forceinline__ float dpp_addf(float x) {
  union { float f; int i; } a, b;
  a.f = x;
  b.i = __builtin_amdgcn_update_dpp(0, a.i, CTRL, 0xF, 0xF, true);
  return x + b.f;
}

// ---------------- fp32 -> bf16 weight conversion ----------------
__global__ void cvt_k(const float* __restrict__ src, __bf16* __restrict__ dst, int n) {
  int i = (blockIdx.x * 256 + threadIdx.x) * 4;
  if (i >= n) return;
  float4 v = *(const float4*)(src + i);
  union { __bf16 h[4]; unsigned long long u; } p;
  p.h[0] = (__bf16)v.x; p.h[1] = (__bf16)v.y; p.h[2] = (__bf16)v.z; p.h[3] = (__bf16)v.w;
  *(unsigned long long*)(dst + i) = p.u;
}

__global__ void cvt3_k(const float* __restrict__ s0, int n0,
                       const float* __restrict__ s1, int n1,
                       const float* __restrict__ s2, int n2,
                       __bf16* __restrict__ dst) {
  int i = (blockIdx.x * 256 + threadIdx.x) * 4;
  const float* s; int off;
  if (i < n0)            { s = s0; off = i; }
  else if (i < n0 + n1)  { s = s1; off = i - n0; }
  else if (i < n0+n1+n2) { s = s2; off = i - n0 - n1; }
  else return;
  float4 v = *(const float4*)(s + off);
  union { __bf16 h[4]; unsigned long long u; } p;
  p.h[0] = (__bf16)v.x; p.h[1] = (__bf16)v.y; p.h[2] = (__bf16)v.z; p.h[3] = (__bf16)v.w;
  *(unsigned long long*)(dst + i) = p.u;
}

// ---------------- im2col for patch embed (bf16 out) ----------------
__global__ void im2col_k(const float* __restrict__ x, __bf16* __restrict__ col) {
  int idx = blockIdx.x * 256 + threadIdx.x;
  if (idx >= PROWS * 768) return;
  int row = idx / 768, i = idx % 768;
  int b = row / NPATCH, p = row % NPATCH;
  int py = p / 14, px = p % 14;
  int ci = i >> 8, rem = i & 255;
  int ky = rem >> 4, kx = rem & 15;
  col[idx] = (__bf16)x[(((size_t)b*3 + ci)*224 + (py*16+ky))*224 + (px*16+kx)];
}

// ---------------- assemble tokens: cls + patches + pos ----------------
__global__ void assemble_k(const float* __restrict__ P, const float* __restrict__ cb,
                           const float* __restrict__ cls, const float* __restrict__ pos,
                           float* __restrict__ t) {
  int bl = blockIdx.x; int b = bl / LSEQ, l = bl % LSEQ;
  for (int c = threadIdx.x; c < 768; c += 256) {
    float v;
    if (l == 0) v = cls[c];
    else        v = P[((size_t)b*NPATCH + (l-1))*768 + c] + cb[c];
    t[(size_t)bl*768 + c] = v + pos[(size_t)l*768 + c];
  }
}

// ---------------- layernorm over 768, templated output dtype ----------------
template<typename T>
__global__ void ln_k(const float* __restrict__ x, const float* __restrict__ w,
                     const float* __restrict__ b, T* __restrict__ o) {
  int row = blockIdx.x;
  const float* xr = x + (size_t)row * 768;
  float v[3]; float s = 0.f, ss = 0.f;
  #pragma unroll
  for (int i = 0; i < 3; i++) {
    v[i] = xr[threadIdx.x + i*256]; s += v[i]; ss += v[i]*v[i];
  }
  __shared__ float red[8];
  #pragma unroll
  for (int off = 32; off; off >>= 1) {
    s  += __shfl_down(s, off, 64);
    ss += __shfl_down(ss, off, 64);
  }
  int wv = threadIdx.x >> 6;
  if ((threadIdx.x & 63) == 0) { red[wv] = s; red[wv+4] = ss; }
  __syncthreads();
  if (threadIdx.x == 0) {
    float S = red[0]+red[1]+red[2]+red[3];
    float SS = red[4]+red[5]+red[6]+red[7];
    float m = S * (1.f/768.f);
    float var = SS * (1.f/768.f) - m*m;
    red[0] = m; red[1] = rsqrtf(var + 1e-5f);
  }
  __syncthreads();
  float m = red[0], r = red[1];
  #pragma unroll
  for (int i = 0; i < 3; i++) {
    int c = threadIdx.x + i*256;
    o[(size_t)row*768 + c] = (T)((v[i]-m)*r*w[c] + b[c]);
  }
}

// ---------------- bf16 MFMA GEMM: C[M,N] = A[M,K] @ W[N,K]^T ----------------
// TM = block M-tile (128 or 64). N-tile fixed 128. 4 waves.
// EPI: 0 = plain fp32, 2 = +aux(resid), 3 = +aux(bias[n]) -> softplus -> transposed
//      store to dvT[(b*D_INNER + n)*LP + l]
template<int EPI, int TM>
__global__ __launch_bounds__(256) void mgemm_k(const __bf16* __restrict__ A,
    const __bf16* __restrict__ W, float* __restrict__ C,
    const float* __restrict__ aux, int M, int N, int K) {
  constexpr int WR = TM / 32;           // 16-row frags per wave in M
  __shared__ __bf16 sA[TM*32];
  __shared__ __bf16 sB[128*32];
  const int tid = threadIdx.x, wave = tid >> 6, lane = tid & 63;
  const int m0 = blockIdx.x * TM, n0 = blockIdx.y * 128;
  const int wm = (wave & 1) * (TM/2), wn = (wave >> 1) * 64;

  floatx4 acc[WR][4] = {};

  const int srow = wave * 16 + (lane >> 2);
  const int scol = (lane & 3) * 8;
  const __bf16* gA0 = A + (size_t)(m0 + srow) * K + scol;
  const __bf16* gA1 = A + (size_t)(m0 + 64 + srow) * K + scol;
  const __bf16* gB0 = W + (size_t)(n0 + srow) * K + scol;
  const __bf16* gB1 = W + (size_t)(n0 + 64 + srow) * K + scol;
  __bf16* lA0 = sA + srow * 32 + scol;
  __bf16* lA1 = lA0 + 64 * 32;
  __bf16* lB0 = sB + srow * 32 + scol;
  __bf16* lB1 = lB0 + 64 * 32;

  const __bf16* pA = sA + (wm + (lane & 15)) * 32 + (lane >> 4) * 8;
  const __bf16* pB = sB + (wn + (lane & 15)) * 32 + (lane >> 4) * 8;

  for (int k0 = 0; k0 < K; k0 += 32) {
    gload_lds16(gA0 + k0, lA0);
    if (TM == 128) gload_lds16(gA1 + k0, lA1);
    gload_lds16(gB0 + k0, lB0);
    gload_lds16(gB1 + k0, lB1);
    __syncthreads();
    bf16x8 af[WR], bfr[4];
    #pragma unroll
    for (int i = 0; i < WR; i++) af[i]  = *(const bf16x8*)(pA + i * 16 * 32);
    #pragma unroll
    for (int j = 0; j < 4; j++)  bfr[j] = *(const bf16x8*)(pB + j * 16 * 32);
    #pragma unroll
    for (int i = 0; i < WR; i++)
      #pragma unroll
      for (int j = 0; j < 4; j++)
        acc[i][j] = __builtin_amdgcn_mfma_f32_16x16x32_bf16(af[i], bfr[j], acc[i][j], 0, 0, 0);
    __syncthreads();
  }

  const int en = n0 + wn + (lane & 15);
  const int em = m0 + wm + (lane >> 4) * 4;
  if (EPI == 3) {
    #pragma unroll
    for (int i = 0; i < WR; i++) {
      int mr = em + i * 16;
      int b0 = mr / LSEQ, l0 = mr - b0 * LSEQ;
      bool fast = (l0 + 3 < LSEQ) && (mr + 3 < M);
      #pragma unroll
      for (int j = 0; j < 4; j++) {
        int d = en + j * 16;
        float bv = aux[d];
        float* p = C + ((size_t)b0 * D_INNER + d) * LP + l0;
        if (fast) {
          #pragma unroll
          for (int r = 0; r < 4; r++) {
            float v = acc[i][j][r] + bv;
            p[r] = (v > 20.f) ? v : log1pf(__expf(v));
          }
        } else {
          #pragma unroll
          for (int r = 0; r < 4; r++) {
            int m = mr + r;
            if (m >= M) continue;
            int bb = m / LSEQ, ll = m - bb * LSEQ;
            float v = acc[i][j][r] + bv;
            C[((size_t)bb * D_INNER + d) * LP + ll] = (v > 20.f) ? v : log1pf(__expf(v));
          }
        }
      }
    }
  } else {
    #pragma unroll
    for (int i = 0; i < WR; i++) {
      #pragma unroll
      for (int r = 0; r < 4; r++) {
        int m = em + i * 16 + r;
        if (m >= M) continue;
        #pragma unroll
        for (int j = 0; j < 4; j++) {
          int n = en + j * 16;
          float v = acc[i][j][r];
          if (EPI == 2) v += aux[(size_t)m * N + n];
          C[(size_t)m * N + n] = v;
        }
      }
    }
  }
}

// ---------------- fused depthwise conv1d + silu + gate-prep ----------------
__global__ __launch_bounds__(256) void convf_k(const float* __restrict__ xz,
    const float* __restrict__ cw, const float* __restrict__ cb,
    const float* __restrict__ Dp, __bf16* __restrict__ xc_b,
    float* __restrict__ xvT, float* __restrict__ gmT, float* __restrict__ gaT) {
  const int b = blockIdx.x, dc = blockIdx.y, lc = blockIdx.z * 52;
  const int d = dc * 256 + threadIdx.x;
  const int lend = min(lc + 52, LSEQ);
  const float* w = cw + (size_t)d * 4;
  const float w0 = w[0], w1 = w[1], w2 = w[2], w3 = w[3];
  const float bias = cb[d], dp = Dp[d];
  float xm3 = 0.f, xm2 = 0.f, xm1 = 0.f;
  const size_t rowbase = ((size_t)b * LSEQ) * 3072 + d;
  if (lc >= 3) {
    xm3 = xz[rowbase + (size_t)(lc-3)*3072];
    xm2 = xz[rowbase + (size_t)(lc-2)*3072];
    xm1 = xz[rowbase + (size_t)(lc-1)*3072];
  }
  const size_t ch = (size_t)b * D_INNER + d;
  float* pxv = xvT + ch * LP;
  float* pgm = gmT + ch * LP;
  float* pga = gaT + ch * LP;

  int l = lc;
  for (; l + 3 < lend; l += 4) {
    float4 bxv, bgm, bga;
    #pragma unroll
    for (int q = 0; q < 4; q++) {
      int lq = l + q;
      float x0 = xz[rowbase + (size_t)lq*3072];
      float zc = xz[rowbase + (size_t)lq*3072 + 1536];
      float c = w0*xm3 + w1*xm2 + w2*xm1 + w3*x0 + bias;
      xm3 = xm2; xm2 = xm1; xm1 = x0;
      float xc = siluf(c);
      float gm = siluf(zc);
      (&bxv.x)[q] = xc; (&bgm.x)[q] = gm; (&bga.x)[q] = dp*xc*gm;
      xc_b[((size_t)b*LSEQ + lq)*D_INNER + d] = (__bf16)xc;
    }
    *(float4*)(pxv + l) = bxv;
    *(float4*)(pgm + l) = bgm;
    *(float4*)(pga + l) = bga;
  }
  for (; l < lend; l++) {
    float x0 = xz[rowbase + (size_t)l*3072];
    float zc = xz[rowbase + (size_t)l*3072 + 1536];
    float c = w0*xm3 + w1*xm2 + w2*xm1 + w3*x0 + bias;
    xm3 = xm2; xm2 = xm1; xm1 = x0;
    float xc = siluf(c);
    float gm = siluf(zc);
    xc_b[((size_t)b*LSEQ + l)*D_INNER + d] = (__bf16)xc;
    pxv[l] = xc; pgm[l] = gm; pga[l] = dp*xc*gm;
  }
}

// ---------------- x_proj -> transposed BsT[(b*16+n)*LP + l] ----------------
__global__ void xproj_k(const __bf16* __restrict__ xc, const float* __restrict__ xpw,
                        float* __restrict__ BsT) {
  int row = blockIdx.x;
  int b = row / LSEQ, l = row - b * LSEQ;
  int n = threadIdx.x & 15, stripe = threadIdx.x >> 4;
  const __bf16* xr = xc + (size_t)row * D_INNER;
  const float* wr = xpw + (size_t)n * D_INNER;
  float s = 0.f;
  int k0 = stripe * 96;
  for (int k = k0; k < k0 + 96; k++) s += (float)xr[k] * wr[k];
  __shared__ float red[16][17];
  red[stripe][n] = s;
  __syncthreads();
  if (threadIdx.x < 16) {
    float t = 0.f;
    #pragma unroll
    for (int i = 0; i < 16; i++) t += red[i][threadIdx.x];
    BsT[((size_t)b*16 + threadIdx.x)*LP + l] = t;
  }
}

// ---------------- selective scan: register-chunk + DPP butterfly ----------------
// 16 lanes per channel (lane = state index n). Per 16-step chunk, bulk-load
// dv/xv (shared across group) and B_n time-series into registers; inner loop
// is pure VALU + 4 DPP adds. No DS ops, no per-step memory ops.
__global__ __launch_bounds__(256) void scan3_k(const float* __restrict__ dvT,
    const float* __restrict__ xvT, const float* __restrict__ gmT,
    const float* __restrict__ gaT, const float* __restrict__ BsT,
    const float* __restrict__ A_log, __bf16* __restrict__ y) {
  const int grp = threadIdx.x >> 4, n = threadIdx.x & 15;
  const int ch = blockIdx.x * 16 + grp;
  const int b = ch / D_INNER, d = ch - b * D_INNER;
  const float a = -__expf(A_log[(size_t)d * 16 + n]);
  const size_t base = (size_t)ch * LP;
  const size_t bnb  = ((size_t)b * 16 + n) * LP;
  const size_t brow = (size_t)b * LSEQ;
  float s = 0.f;
  for (int l0 = 0; l0 < LP; l0 += 16) {
    float dv[16], xv[16], bn[16];
    #pragma unroll
    for (int q = 0; q < 4; q++) {
      *(float4*)(dv + q*4) = *(const float4*)(dvT + base + l0 + q*4);
      *(float4*)(xv + q*4) = *(const float4*)(xvT + base + l0 + q*4);
      *(float4*)(bn + q*4) = *(const float4*)(BsT + bnb  + l0 + q*4);
    }
    float gm = gmT[base + l0 + n];
    float ga = gaT[base + l0 + n];
    float yreg = 0.f;
    #pragma unroll
    for (int j = 0; j < 16; j++) {
      s = __expf(dv[j] * a) * s + (dv[j] * xv[j]) * bn[j];
      float part = s * bn[j];
      part = dpp_addf<0xB1>(part);    // xor 1 (quad_perm)
      part = dpp_addf<0x4E>(part);    // xor 2 (quad_perm)
      part = dpp_addf<0x141>(part);   // xor 7 (row_half_mirror)
      part = dpp_addf<0x140>(part);   // xor 15 (row_mirror)
      yreg = (n == j) ? part : yreg;
    }
    int lo = l0 + n;
    if (lo < LSEQ) y[(brow + lo) * D_INNER + d] = (__bf16)(yreg * gm + ga);
  }
}

extern "C" void kernel_launch(void* const* d_in, const int* in_sizes, int n_in,
                              void* d_out, int out_size, void* d_ws, size_t ws_size,
                              hipStream_t stream) {
  const float* x         = (const float*)d_in[0];
  const float* conv_w    = (const float*)d_in[1];
  const float* conv_b    = (const float*)d_in[2];
  const float* cls_token = (const float*)d_in[3];
  const float* pos_embed = (const float*)d_in[4];
  const float* ln_w      = (const float*)d_in[5];
  const float* ln_b      = (const float*)d_in[6];
  const float* in_proj_w = (const float*)d_in[7];
  const float* conv1d_w  = (const float*)d_in[8];
  const float* conv1d_b  = (const float*)d_in[9];
  const float* x_proj_w  = (const float*)d_in[10];
  const float* dt_proj_w = (const float*)d_in[11];
  const float* dt_proj_b = (const float*)d_in[12];
  const float* A_log     = (const float*)d_in[13];
  const float* D_param   = (const float*)d_in[14];
  const float* out_proj_w= (const float*)d_in[15];
  const float* norm_w    = (const float*)d_in[16];
  const float* norm_b    = (const float*)d_in[17];

  const int N_IN  = 2*D_INNER*D_MODEL;
  const int N_DT  = D_INNER*D_INNER;
  const int N_OUT = D_MODEL*D_INNER;
  const size_t TSZ = (size_t)BATCH * D_INNER * LP * 4;

  char* wsb = (char*)d_ws;
  size_t off = 0;
  float* t     = (float*)(wsb + off); off += (size_t)ROWS*768*4;
  float* xz    = (float*)(wsb + off); off += (size_t)ROWS*3072*4;
  float* BsT   = (float*)(wsb + off); off += (size_t)BATCH*16*LP*4;
  float* dvT   = (float*)(wsb + off); off += TSZ;
  float* xvT   = (float*)(wsb + off); off += TSZ;
  float* gmT   = (float*)(wsb + off); off += TSZ;
  float* gaT   = (float*)(wsb + off); off += TSZ;
  __bf16* xn_b = (__bf16*)(wsb + off); off += (size_t)MPAD*768*2;
  __bf16* xc_b = (__bf16*)(wsb + off); off += (size_t)MPAD*1536*2;
  __bf16* y_b  = (__bf16*)(wsb + off); off += (size_t)MPAD*1536*2;
  __bf16* col_b= (__bf16*)(wsb + off); off += (size_t)MPAD*768*2;
  __bf16* cw_b = (__bf16*)(wsb + off); off += (size_t)768*768*2;
  __bf16* wbuf = (__bf16*)(wsb + off); off += (size_t)(N_IN+N_DT+N_OUT)*2;

  // ---- patch embed as bf16 MFMA GEMM ----
  float* P = xz;  // reuse
  im2col_k<<<(PROWS*768 + 255)/256, 256, 0, stream>>>(x, col_b);
  cvt_k<<<(768*768/4 + 255)/256, 256, 0, stream>>>(conv_w, cw_b, 768*768);
  mgemm_k<0,64><<<dim3(25, 6), 256, 0, stream>>>(col_b, cw_b, P, nullptr, PROWS, 768, 768);
  assemble_k<<<ROWS, 256, 0, stream>>>(P, conv_b, cls_token, pos_embed, t);

  for (int i = 0; i < DEPTH; i++) {
    cvt3_k<<<(N_IN+N_DT+N_OUT)/4/256, 256, 0, stream>>>(
        in_proj_w + (size_t)i*N_IN, N_IN,
        dt_proj_w + (size_t)i*N_DT, N_DT,
        out_proj_w + (size_t)i*N_OUT, N_OUT, wbuf);
    ln_k<__bf16><<<ROWS, 256, 0, stream>>>(t, ln_w + (size_t)i*768, ln_b + (size_t)i*768, xn_b);
    mgemm_k<0,128><<<dim3(13, 24), 256, 0, stream>>>(xn_b, wbuf, xz, nullptr, ROWS, 3072, 768);
    convf_k<<<dim3(8, 6, 4), 256, 0, stream>>>(xz, conv1d_w + (size_t)i*D_INNER*4,
        conv1d_b + (size_t)i*D_INNER, D_param + (size_t)i*D_INNER,
        xc_b, xvT, gmT, gaT);
    xproj_k<<<ROWS, 256, 0, stream>>>(xc_b, x_proj_w + (size_t)i*32*D_INNER + 16*D_INNER, BsT);
    mgemm_k<3,64><<<dim3(25, 12), 256, 0, stream>>>(xc_b, wbuf + N_IN, dvT,
                                                    dt_proj_b + (size_t)i*D_INNER,
                                                    ROWS, 1536, 1536);
    scan3_k<<<(BATCH*D_INNER)/16, 256, 0, stream>>>(dvT, xvT, gmT, gaT, BsT,
        A_log + (size_t)i*D_INNER*D_STATE, y_b);
    mgemm_k<2,64><<<dim3(25, 6), 256, 0, stream>>>(y_b, wbuf + N_IN + N_DT, t, t,
                                                   ROWS, 768, D_INNER);
  }

  ln_k<float><<<ROWS, 256, 0, stream>>>(t, norm_w, norm_b, (float*)d_out);
}

// Round 5
// 2134.057 us; speedup vs baseline: 5.5923x; 1.2523x over previous
//
#include <hip/hip_runtime.h>
#include <math.h>

#define D_MODEL 768
#define D_INNER 1536
#define D_STATE 16
#define DEPTH   12
#define LSEQ    197
#define BATCH   8
#define NPATCH  196
#define ROWS    (BATCH*LSEQ)    // 1576
#define PROWS   (BATCH*NPATCH)  // 1568
#define MPAD    1664            // 26*64, padded row count for bf16 A operands
#define LP      208             // padded time axis for transposed scan arrays (13*16)

typedef __bf16 bf16x8 __attribute__((ext_vector_type(8)));
typedef float  floatx4 __attribute__((ext_vector_type(4)));
typedef __attribute__((address_space(1))) void gvoid;
typedef __attribute__((address_space(3))) void svoid;

__device__ __forceinline__ float siluf(float x) { return x / (1.f + __expf(-x)); }

__device__ __forceinline__ void gload_lds16(const void* g, void* s) {
  __builtin_amdgcn_global_load_lds((const gvoid*)g, (svoid*)s, 16, 0, 0);
}

// DPP cross-lane add within 16-lane rows (VALU pipe, no DS).
template<int CTRL>
__device__ __forceinline__ float dpp_addf(float x) {
  union { float f; int i; } a, b;
  a.f = x;
  b.i = __builtin_amdgcn_update_dpp(0, a.i, CTRL, 0xF, 0xF, true);
  return x + b.f;
}

// ---------------- fp32 -> bf16 weight conversion ----------------
__global__ void cvt_k(const float* __restrict__ src, __bf16* __restrict__ dst, int n) {
  int i = (blockIdx.x * 256 + threadIdx.x) * 4;
  if (i >= n) return;
  float4 v = *(const float4*)(src + i);
  union { __bf16 h[4]; unsigned long long u; } p;
  p.h[0] = (__bf16)v.x; p.h[1] = (__bf16)v.y; p.h[2] = (__bf16)v.z; p.h[3] = (__bf16)v.w;
  *(unsigned long long*)(dst + i) = p.u;
}

__global__ void cvt3_k(const float* __restrict__ s0, int n0,
                       const float* __restrict__ s1, int n1,
                       const float* __restrict__ s2, int n2,
                       __bf16* __restrict__ dst) {
  int i = (blockIdx.x * 256 + threadIdx.x) * 4;
  const float* s; int off;
  if (i < n0)            { s = s0; off = i; }
  else if (i < n0 + n1)  { s = s1; off = i - n0; }
  else if (i < n0+n1+n2) { s = s2; off = i - n0 - n1; }
  else return;
  float4 v = *(const float4*)(s + off);
  union { __bf16 h[4]; unsigned long long u; } p;
  p.h[0] = (__bf16)v.x; p.h[1] = (__bf16)v.y; p.h[2] = (__bf16)v.z; p.h[3] = (__bf16)v.w;
  *(unsigned long long*)(dst + i) = p.u;
}

// ---------------- im2col for patch embed (bf16 out) ----------------
__global__ void im2col_k(const float* __restrict__ x, __bf16* __restrict__ col) {
  int idx = blockIdx.x * 256 + threadIdx.x;
  if (idx >= PROWS * 768) return;
  int row = idx / 768, i = idx % 768;
  int b = row / NPATCH, p = row % NPATCH;
  int py = p / 14, px = p % 14;
  int ci = i >> 8, rem = i & 255;
  int ky = rem >> 4, kx = rem & 15;
  col[idx] = (__bf16)x[(((size_t)b*3 + ci)*224 + (py*16+ky))*224 + (px*16+kx)];
}

// ---------------- assemble tokens: cls + patches + pos ----------------
__global__ void assemble_k(const float* __restrict__ P, const float* __restrict__ cb,
                           const float* __restrict__ cls, const float* __restrict__ pos,
                           float* __restrict__ t) {
  int bl = blockIdx.x; int b = bl / LSEQ, l = bl % LSEQ;
  for (int c = threadIdx.x; c < 768; c += 256) {
    float v;
    if (l == 0) v = cls[c];
    else        v = P[((size_t)b*NPATCH + (l-1))*768 + c] + cb[c];
    t[(size_t)bl*768 + c] = v + pos[(size_t)l*768 + c];
  }
}

// ---------------- layernorm over 768, templated output dtype ----------------
template<typename T>
__global__ void ln_k(const float* __restrict__ x, const float* __restrict__ w,
                     const float* __restrict__ b, T* __restrict__ o) {
  int row = blockIdx.x;
  const float* xr = x + (size_t)row * 768;
  float v[3]; float s = 0.f, ss = 0.f;
  #pragma unroll
  for (int i = 0; i < 3; i++) {
    v[i] = xr[threadIdx.x + i*256]; s += v[i]; ss += v[i]*v[i];
  }
  __shared__ float red[8];
  #pragma unroll
  for (int off = 32; off; off >>= 1) {
    s  += __shfl_down(s, off, 64);
    ss += __shfl_down(ss, off, 64);
  }
  int wv = threadIdx.x >> 6;
  if ((threadIdx.x & 63) == 0) { red[wv] = s; red[wv+4] = ss; }
  __syncthreads();
  if (threadIdx.x == 0) {
    float S = red[0]+red[1]+red[2]+red[3];
    float SS = red[4]+red[5]+red[6]+red[7];
    float m = S * (1.f/768.f);
    float var = SS * (1.f/768.f) - m*m;
    red[0] = m; red[1] = rsqrtf(var + 1e-5f);
  }
  __syncthreads();
  float m = red[0], r = red[1];
  #pragma unroll
  for (int i = 0; i < 3; i++) {
    int c = threadIdx.x + i*256;
    o[(size_t)row*768 + c] = (T)((v[i]-m)*r*w[c] + b[c]);
  }
}

// ---------------- bf16 MFMA GEMM v2: TM=64, TN=128, BK=64 ----------------
// Double-buffered LDS, one barrier per K-iter (prefetch issued after barrier,
// drained by the NEXT barrier's vmcnt(0) -> one compute-phase of latency hiding).
// Global-source XOR swizzle (granule ^= row&7) keeps ds_read_b128 conflict-free
// while LDS dest stays lane-linear (required by global_load_lds).
// Plain fp32 store to C + blockIdx.z*pstride (split-K partials when gridDim.z>1).
__global__ __launch_bounds__(256) void mgemm2_k(const __bf16* __restrict__ A,
    const __bf16* __restrict__ W, float* __restrict__ C, size_t pstride,
    int M, int N, int K, int Ksub) {
  __shared__ __bf16 sA[2][64*64];
  __shared__ __bf16 sB[2][128*64];
  const int tid = threadIdx.x, wave = tid >> 6, lane = tid & 63;
  const int m0 = blockIdx.x * 64, n0 = blockIdx.y * 128;
  const int wm = (wave & 1) * 32, wn = (wave >> 1) * 64;
  const int kbeg = blockIdx.z * Ksub, kend = kbeg + Ksub;

  floatx4 acc[2][4] = {};

  // staging: pass p covers rows p*32..p*32+31; thread t -> row p*32+(t>>3),
  // LDS granule t&7, global granule (t&7)^(row&7).
  const int srow = tid >> 3;
  const int scol = ((tid & 7) ^ (srow & 7)) * 8;
  const __bf16* gA = A + (size_t)(m0 + srow) * K + scol;
  const __bf16* gB = W + (size_t)(n0 + srow) * K + scol;

  // fragment read offsets: row R = w?+i*16+(lane&15); R&7 == lane&7.
  const int lm = lane & 15, lk = lane >> 4;
  const int g0 = ((lk    ) ^ (lane & 7)) * 8;   // k-half 0 granule (elems)
  const int g1 = ((lk + 4) ^ (lane & 7)) * 8;   // k-half 1

  int buf = 0;
  {  // prologue stage into buf 0
    #pragma unroll
    for (int p = 0; p < 2; p++)
      gload_lds16(gA + (size_t)(p*32)*K + kbeg, sA[0] + p*2048 + tid*8);
    #pragma unroll
    for (int p = 0; p < 4; p++)
      gload_lds16(gB + (size_t)(p*32)*K + kbeg, sB[0] + p*2048 + tid*8);
  }

  for (int k0 = kbeg; k0 < kend; k0 += 64) {
    __syncthreads();
    if (k0 + 64 < kend) {
      const int nb = buf ^ 1;
      #pragma unroll
      for (int p = 0; p < 2; p++)
        gload_lds16(gA + (size_t)(p*32)*K + (k0+64), sA[nb] + p*2048 + tid*8);
      #pragma unroll
      for (int p = 0; p < 4; p++)
        gload_lds16(gB + (size_t)(p*32)*K + (k0+64), sB[nb] + p*2048 + tid*8);
    }
    const __bf16* pA = sA[buf] + (wm + lm) * 64;
    const __bf16* pB = sB[buf] + (wn + lm) * 64;
    bf16x8 a0[2], a1[2], b0[4], b1[4];
    #pragma unroll
    for (int i = 0; i < 2; i++) {
      a0[i] = *(const bf16x8*)(pA + i*1024 + g0);
      a1[i] = *(const bf16x8*)(pA + i*1024 + g1);
    }
    #pragma unroll
    for (int j = 0; j < 4; j++) {
      b0[j] = *(const bf16x8*)(pB + j*1024 + g0);
      b1[j] = *(const bf16x8*)(pB + j*1024 + g1);
    }
    #pragma unroll
    for (int i = 0; i < 2; i++)
      #pragma unroll
      for (int j = 0; j < 4; j++) {
        acc[i][j] = __builtin_amdgcn_mfma_f32_16x16x32_bf16(a0[i], b0[j], acc[i][j], 0, 0, 0);
        acc[i][j] = __builtin_amdgcn_mfma_f32_16x16x32_bf16(a1[i], b1[j], acc[i][j], 0, 0, 0);
      }
    buf ^= 1;
  }

  float* Cp = C + blockIdx.z * pstride;
  const int en = n0 + wn + lm;
  const int em = m0 + wm + lk * 4;
  #pragma unroll
  for (int i = 0; i < 2; i++) {
    #pragma unroll
    for (int r = 0; r < 4; r++) {
      int m = em + i * 16 + r;
      if (m >= M) continue;
      #pragma unroll
      for (int j = 0; j < 4; j++)
        Cp[(size_t)m * N + en + j * 16] = acc[i][j][r];
    }
  }
}

// ---------------- split-K reduce for dt: +bias, softplus, transpose -> dvT ----
// grid (8, 24, 7); tile 64 d x 32 l, LDS transpose, coalesced both sides.
__global__ __launch_bounds__(256) void reduce_dt_k(const float* __restrict__ p0,
    const float* __restrict__ bias, float* __restrict__ dvT) {
  __shared__ float s[32 * 65];
  const float* p1 = p0 + (size_t)ROWS * D_INNER;
  const int b = blockIdx.x, d0 = blockIdx.y * 64, l0 = blockIdx.z * 32;
  const int t = threadIdx.x;
  #pragma unroll
  for (int e = 0; e < 8; e++) {
    int idx = e * 256 + t;
    int d = idx & 63, l = idx >> 6;
    float v = 0.f;
    int gl = l0 + l;
    if (gl < LSEQ) {
      size_t row = (size_t)(b * LSEQ + gl) * D_INNER + d0 + d;
      v = p0[row] + p1[row] + bias[d0 + d];
      v = (v > 20.f) ? v : log1pf(__expf(v));
    }
    s[l * 65 + d] = v;
  }
  __syncthreads();
  #pragma unroll
  for (int e = 0; e < 8; e++) {
    int idx = e * 256 + t;
    int ll = idx & 31, dd = idx >> 5;
    int gl = l0 + ll;
    if (gl < LP)
      dvT[((size_t)b * D_INNER + d0 + dd) * LP + gl] = s[ll * 65 + dd];
  }
}

// ---------------- split-K reduce for out_proj: sum 4 partials + residual ----
__global__ void reduce_out_k(const float* __restrict__ part, float* __restrict__ t) {
  int i = (blockIdx.x * 256 + threadIdx.x) * 4;
  if (i >= ROWS * 768) return;
  const size_t S = (size_t)ROWS * 768;
  float4 a = *(const float4*)(part + i);
  float4 b = *(const float4*)(part + S + i);
  float4 c = *(const float4*)(part + 2*S + i);
  float4 d = *(const float4*)(part + 3*S + i);
  float4 r = *(const float4*)(t + i);
  r.x += a.x + b.x + c.x + d.x;
  r.y += a.y + b.y + c.y + d.y;
  r.z += a.z + b.z + c.z + d.z;
  r.w += a.w + b.w + c.w + d.w;
  *(float4*)(t + i) = r;
}

// ---------------- fused depthwise conv1d + silu + gate-prep ----------------
__global__ __launch_bounds__(256) void convf_k(const float* __restrict__ xz,
    const float* __restrict__ cw, const float* __restrict__ cb,
    const float* __restrict__ Dp, __bf16* __restrict__ xc_b,
    float* __restrict__ xvT, float* __restrict__ gmT, float* __restrict__ gaT) {
  const int b = blockIdx.x, dc = blockIdx.y, lc = blockIdx.z * 52;
  const int d = dc * 256 + threadIdx.x;
  const int lend = min(lc + 52, LSEQ);
  const float* w = cw + (size_t)d * 4;
  const float w0 = w[0], w1 = w[1], w2 = w[2], w3 = w[3];
  const float bias = cb[d], dp = Dp[d];
  float xm3 = 0.f, xm2 = 0.f, xm1 = 0.f;
  const size_t rowbase = ((size_t)b * LSEQ) * 3072 + d;
  if (lc >= 3) {
    xm3 = xz[rowbase + (size_t)(lc-3)*3072];
    xm2 = xz[rowbase + (size_t)(lc-2)*3072];
    xm1 = xz[rowbase + (size_t)(lc-1)*3072];
  }
  const size_t ch = (size_t)b * D_INNER + d;
  float* pxv = xvT + ch * LP;
  float* pgm = gmT + ch * LP;
  float* pga = gaT + ch * LP;

  int l = lc;
  for (; l + 3 < lend; l += 4) {
    float4 bxv, bgm, bga;
    #pragma unroll
    for (int q = 0; q < 4; q++) {
      int lq = l + q;
      float x0 = xz[rowbase + (size_t)lq*3072];
      float zc = xz[rowbase + (size_t)lq*3072 + 1536];
      float c = w0*xm3 + w1*xm2 + w2*xm1 + w3*x0 + bias;
      xm3 = xm2; xm2 = xm1; xm1 = x0;
      float xc = siluf(c);
      float gm = siluf(zc);
      (&bxv.x)[q] = xc; (&bgm.x)[q] = gm; (&bga.x)[q] = dp*xc*gm;
      xc_b[((size_t)b*LSEQ + lq)*D_INNER + d] = (__bf16)xc;
    }
    *(float4*)(pxv + l) = bxv;
    *(float4*)(pgm + l) = bgm;
    *(float4*)(pga + l) = bga;
  }
  for (; l < lend; l++) {
    float x0 = xz[rowbase + (size_t)l*3072];
    float zc = xz[rowbase + (size_t)l*3072 + 1536];
    float c = w0*xm3 + w1*xm2 + w2*xm1 + w3*x0 + bias;
    xm3 = xm2; xm2 = xm1; xm1 = x0;
    float xc = siluf(c);
    float gm = siluf(zc);
    xc_b[((size_t)b*LSEQ + l)*D_INNER + d] = (__bf16)xc;
    pxv[l] = xc; pgm[l] = gm; pga[l] = dp*xc*gm;
  }
}

// ---------------- x_proj -> transposed BsT[(b*16+n)*LP + l] ----------------
__global__ void xproj_k(const __bf16* __restrict__ xc, const float* __restrict__ xpw,
                        float* __restrict__ BsT) {
  int row = blockIdx.x;
  int b = row / LSEQ, l = row - b * LSEQ;
  int n = threadIdx.x & 15, stripe = threadIdx.x >> 4;
  const __bf16* xr = xc + (size_t)row * D_INNER;
  const float* wr = xpw + (size_t)n * D_INNER;
  float s = 0.f;
  int k0 = stripe * 96;
  for (int k = k0; k < k0 + 96; k++) s += (float)xr[k] * wr[k];
  __shared__ float red[16][17];
  red[stripe][n] = s;
  __syncthreads();
  if (threadIdx.x < 16) {
    float t = 0.f;
    #pragma unroll
    for (int i = 0; i < 16; i++) t += red[i][threadIdx.x];
    BsT[((size_t)b*16 + threadIdx.x)*LP + l] = t;
  }
}

// ---------------- selective scan: register-chunk + DPP butterfly ----------------
__global__ __launch_bounds__(256) void scan3_k(const float* __restrict__ dvT,
    const float* __restrict__ xvT, const float* __restrict__ gmT,
    const float* __restrict__ gaT, const float* __restrict__ BsT,
    const float* __restrict__ A_log, __bf16* __restrict__ y) {
  const int grp = threadIdx.x >> 4, n = threadIdx.x & 15;
  const int ch = blockIdx.x * 16 + grp;
  const int b = ch / D_INNER, d = ch - b * D_INNER;
  const float a = -__expf(A_log[(size_t)d * 16 + n]);
  const size_t base = (size_t)ch * LP;
  const size_t bnb  = ((size_t)b * 16 + n) * LP;
  const size_t brow = (size_t)b * LSEQ;
  float s = 0.f;
  for (int l0 = 0; l0 < LP; l0 += 16) {
    float dv[16], xv[16], bn[16];
    #pragma unroll
    for (int q = 0; q < 4; q++) {
      *(float4*)(dv + q*4) = *(const float4*)(dvT + base + l0 + q*4);
      *(float4*)(xv + q*4) = *(const float4*)(xvT + base + l0 + q*4);
      *(float4*)(bn + q*4) = *(const float4*)(BsT + bnb  + l0 + q*4);
    }
    float gm = gmT[base + l0 + n];
    float ga = gaT[base + l0 + n];
    float yreg = 0.f;
    #pragma unroll
    for (int j = 0; j < 16; j++) {
      s = __expf(dv[j] * a) * s + (dv[j] * xv[j]) * bn[j];
      float part = s * bn[j];
      part = dpp_addf<0xB1>(part);    // xor 1
      part = dpp_addf<0x4E>(part);    // xor 2
      part = dpp_addf<0x141>(part);   // xor 7 (row_half_mirror)
      part = dpp_addf<0x140>(part);   // xor 15 (row_mirror)
      yreg = (n == j) ? part : yreg;
    }
    int lo = l0 + n;
    if (lo < LSEQ) y[(brow + lo) * D_INNER + d] = (__bf16)(yreg * gm + ga);
  }
}

extern "C" void kernel_launch(void* const* d_in, const int* in_sizes, int n_in,
                              void* d_out, int out_size, void* d_ws, size_t ws_size,
                              hipStream_t stream) {
  const float* x         = (const float*)d_in[0];
  const float* conv_w    = (const float*)d_in[1];
  const float* conv_b    = (const float*)d_in[2];
  const float* cls_token = (const float*)d_in[3];
  const float* pos_embed = (const float*)d_in[4];
  const float* ln_w      = (const float*)d_in[5];
  const float* ln_b      = (const float*)d_in[6];
  const float* in_proj_w = (const float*)d_in[7];
  const float* conv1d_w  = (const float*)d_in[8];
  const float* conv1d_b  = (const float*)d_in[9];
  const float* x_proj_w  = (const float*)d_in[10];
  const float* dt_proj_w = (const float*)d_in[11];
  const float* dt_proj_b = (const float*)d_in[12];
  const float* A_log     = (const float*)d_in[13];
  const float* D_param   = (const float*)d_in[14];
  const float* out_proj_w= (const float*)d_in[15];
  const float* norm_w    = (const float*)d_in[16];
  const float* norm_b    = (const float*)d_in[17];

  const int N_IN  = 2*D_INNER*D_MODEL;
  const int N_DT  = D_INNER*D_INNER;
  const int N_OUT = D_MODEL*D_INNER;
  const size_t TSZ = (size_t)BATCH * D_INNER * LP * 4;

  char* wsb = (char*)d_ws;
  size_t off = 0;
  float* t     = (float*)(wsb + off); off += (size_t)ROWS*768*4;
  float* xz    = (float*)(wsb + off); off += (size_t)ROWS*3072*4;  // also split-K partials
  float* BsT   = (float*)(wsb + off); off += (size_t)BATCH*16*LP*4;
  float* dvT   = (float*)(wsb + off); off += TSZ;
  float* xvT   = (float*)(wsb + off); off += TSZ;
  float* gmT   = (float*)(wsb + off); off += TSZ;
  float* gaT   = (float*)(wsb + off); off += TSZ;
  __bf16* xn_b = (__bf16*)(wsb + off); off += (size_t)MPAD*768*2;
  __bf16* xc_b = (__bf16*)(wsb + off); off += (size_t)MPAD*1536*2;
  __bf16* y_b  = (__bf16*)(wsb + off); off += (size_t)MPAD*1536*2;
  __bf16* col_b= (__bf16*)(wsb + off); off += (size_t)MPAD*768*2;
  __bf16* cw_b = (__bf16*)(wsb + off); off += (size_t)768*768*2;
  __bf16* wbuf = (__bf16*)(wsb + off); off += (size_t)(N_IN+N_DT+N_OUT)*2;

  float* part = xz;  // xz is free between convf (last reader) and next in_proj

  // ---- patch embed as bf16 MFMA GEMM ----
  float* P = xz;  // reuse
  im2col_k<<<(PROWS*768 + 255)/256, 256, 0, stream>>>(x, col_b);
  cvt_k<<<(768*768/4 + 255)/256, 256, 0, stream>>>(conv_w, cw_b, 768*768);
  mgemm2_k<<<dim3(25, 6, 1), 256, 0, stream>>>(col_b, cw_b, P, 0, PROWS, 768, 768, 768);
  assemble_k<<<ROWS, 256, 0, stream>>>(P, conv_b, cls_token, pos_embed, t);

  for (int i = 0; i < DEPTH; i++) {
    cvt3_k<<<(N_IN+N_DT+N_OUT)/4/256, 256, 0, stream>>>(
        in_proj_w + (size_t)i*N_IN, N_IN,
        dt_proj_w + (size_t)i*N_DT, N_DT,
        out_proj_w + (size_t)i*N_OUT, N_OUT, wbuf);
    ln_k<__bf16><<<ROWS, 256, 0, stream>>>(t, ln_w + (size_t)i*768, ln_b + (size_t)i*768, xn_b);
    mgemm2_k<<<dim3(25, 24, 1), 256, 0, stream>>>(xn_b, wbuf, xz, 0, ROWS, 3072, 768, 768);
    convf_k<<<dim3(8, 6, 4), 256, 0, stream>>>(xz, conv1d_w + (size_t)i*D_INNER*4,
        conv1d_b + (size_t)i*D_INNER, D_param + (size_t)i*D_INNER,
        xc_b, xvT, gmT, gaT);
    xproj_k<<<ROWS, 256, 0, stream>>>(xc_b, x_proj_w + (size_t)i*32*D_INNER + 16*D_INNER, BsT);
    // dt_proj: split-K x2 into partials (xz), then reduce+softplus+transpose
    mgemm2_k<<<dim3(25, 12, 2), 256, 0, stream>>>(xc_b, wbuf + N_IN, part,
        (size_t)ROWS*D_INNER, ROWS, 1536, 1536, 768);
    reduce_dt_k<<<dim3(8, 24, 7), 256, 0, stream>>>(part,
        dt_proj_b + (size_t)i*D_INNER, dvT);
    scan3_k<<<(BATCH*D_INNER)/16, 256, 0, stream>>>(dvT, xvT, gmT, gaT, BsT,
        A_log + (size_t)i*D_INNER*D_STATE, y_b);
    // out_proj: split-K x4 into partials (xz), then reduce + residual into t
    mgemm2_k<<<dim3(25, 6, 4), 256, 0, stream>>>(y_b, wbuf + N_IN + N_DT, part,
        (size_t)ROWS*768, ROWS, 768, 1536, 384);
    reduce_out_k<<<(ROWS*768/4 + 255)/256, 256, 0, stream>>>(part, t);
  }

  ln_k<float><<<ROWS, 256, 0, stream>>>(t, norm_w, norm_b, (float*)d_out);
}

// Round 6
// 2115.590 us; speedup vs baseline: 5.6411x; 1.0087x over previous
//
#include <hip/hip_runtime.h>
#include <math.h>

#define D_MODEL 768
#define D_INNER 1536
#define D_STATE 16
#define DEPTH   12
#define LSEQ    197
#define BATCH   8
#define NPATCH  196
#define ROWS    (BATCH*LSEQ)    // 1576
#define PROWS   (BATCH*NPATCH)  // 1568
#define MPAD    1664            // 26*64, padded row count for bf16 A operands
#define LP      208             // padded time axis for transposed scan arrays (13*16)

typedef __bf16 bf16x8 __attribute__((ext_vector_type(8)));
typedef float  floatx4 __attribute__((ext_vector_type(4)));
typedef __attribute__((address_space(1))) void gvoid;
typedef __attribute__((address_space(3))) void svoid;

__device__ __forceinline__ float siluf(float x) { return x / (1.f + __expf(-x)); }

__device__ __forceinline__ void gload_lds16(const void* g, void* s) {
  __builtin_amdgcn_global_load_lds((const gvoid*)g, (svoid*)s, 16, 0, 0);
}

// DPP cross-lane add within 16-lane rows (VALU pipe, no DS).
template<int CTRL>
__device__ __forceinline__ float dpp_addf(float x) {
  union { float f; int i; } a, b;
  a.f = x;
  b.i = __builtin_amdgcn_update_dpp(0, a.i, CTRL, 0xF, 0xF, true);
  return x + b.f;
}

// ---------------- fp32 -> bf16 conversion (vectorized, n % 4 == 0) ----------------
__global__ void cvt_k(const float* __restrict__ src, __bf16* __restrict__ dst, int n) {
  int i = (blockIdx.x * 256 + threadIdx.x) * 4;
  if (i >= n) return;
  float4 v = *(const float4*)(src + i);
  union { __bf16 h[4]; unsigned long long u; } p;
  p.h[0] = (__bf16)v.x; p.h[1] = (__bf16)v.y; p.h[2] = (__bf16)v.z; p.h[3] = (__bf16)v.w;
  *(unsigned long long*)(dst + i) = p.u;
}

// ---------------- im2col for patch embed (bf16 out) ----------------
__global__ void im2col_k(const float* __restrict__ x, __bf16* __restrict__ col) {
  int idx = blockIdx.x * 256 + threadIdx.x;
  if (idx >= PROWS * 768) return;
  int row = idx / 768, i = idx % 768;
  int b = row / NPATCH, p = row % NPATCH;
  int py = p / 14, px = p % 14;
  int ci = i >> 8, rem = i & 255;
  int ky = rem >> 4, kx = rem & 15;
  col[idx] = (__bf16)x[(((size_t)b*3 + ci)*224 + (py*16+ky))*224 + (px*16+kx)];
}

// ---------------- assemble tokens: cls + patches + pos ----------------
__global__ void assemble_k(const float* __restrict__ P, const float* __restrict__ cb,
                           const float* __restrict__ cls, const float* __restrict__ pos,
                           float* __restrict__ t) {
  int bl = blockIdx.x; int b = bl / LSEQ, l = bl % LSEQ;
  for (int c = threadIdx.x; c < 768; c += 256) {
    float v;
    if (l == 0) v = cls[c];
    else        v = P[((size_t)b*NPATCH + (l-1))*768 + c] + cb[c];
    t[(size_t)bl*768 + c] = v + pos[(size_t)l*768 + c];
  }
}

// ---------------- layernorm over 768 with optional fused split-K residual ----
// FUSE: 0 = plain LN(t); 1 = t += sum(4 partials), store t, LN; 2 = same but
// don't store t (final layer).
template<typename T, int FUSE>
__global__ void lnf_k(float* __restrict__ t, const float* __restrict__ part,
                      const float* __restrict__ w, const float* __restrict__ b,
                      T* __restrict__ o) {
  int row = blockIdx.x;
  float* tr = t + (size_t)row * 768;
  float v[3]; float s = 0.f, ss = 0.f;
  #pragma unroll
  for (int i = 0; i < 3; i++) {
    int c = threadIdx.x + i*256;
    float x = tr[c];
    if (FUSE) {
      const size_t S = (size_t)ROWS*768, idx = (size_t)row*768 + c;
      x += part[idx] + part[S+idx] + part[2*S+idx] + part[3*S+idx];
      if (FUSE == 1) tr[c] = x;
    }
    v[i] = x; s += x; ss += x*x;
  }
  __shared__ float red[8];
  #pragma unroll
  for (int off = 32; off; off >>= 1) {
    s  += __shfl_down(s, off, 64);
    ss += __shfl_down(ss, off, 64);
  }
  int wv = threadIdx.x >> 6;
  if ((threadIdx.x & 63) == 0) { red[wv] = s; red[wv+4] = ss; }
  __syncthreads();
  if (threadIdx.x == 0) {
    float S = red[0]+red[1]+red[2]+red[3];
    float SS = red[4]+red[5]+red[6]+red[7];
    float m = S * (1.f/768.f);
    float var = SS * (1.f/768.f) - m*m;
    red[0] = m; red[1] = rsqrtf(var + 1e-5f);
  }
  __syncthreads();
  float m = red[0], r = red[1];
  #pragma unroll
  for (int i = 0; i < 3; i++) {
    int c = threadIdx.x + i*256;
    o[(size_t)row*768 + c] = (T)((v[i]-m)*r*w[c] + b[c]);
  }
}

// ---------------- bf16 MFMA GEMM v3: TM=64, TN=128, BK=64, XCD swizzle ------
// 1D grid = MT * combos, combos = nt * nz. When combos % 8 == 0, blocks sharing
// one (n-tile, k-split) combo all land on one XCD (blockIdx % 8 -> XCD round-
// robin), so each XCD's L2 holds only its ~590 KB weight slice -> B loads hit L2.
// Double-buffered LDS, one barrier/iter; XOR-swizzled LDS reads, lane-linear
// LDS writes (required by global_load_lds). Split-K partial to C + z*pstride.
__global__ __launch_bounds__(256) void mgemm3_k(const __bf16* __restrict__ A,
    const __bf16* __restrict__ W, float* __restrict__ C, size_t pstride,
    int M, int N, int K, int Ksub, int combos, int nt) {
  __shared__ __bf16 sA[2][64*64];
  __shared__ __bf16 sB[2][128*64];
  const int lin = blockIdx.x;
  int c, mt;
  if ((combos & 7) == 0) {
    const int g = combos >> 3, hi = lin >> 3;
    c  = (lin & 7) + ((hi % g) << 3);
    mt = hi / g;
  } else { c = lin % combos; mt = lin / combos; }
  const int ntile = c % nt, z = c / nt;
  const int m0 = mt * 64, n0 = ntile * 128;
  const int kbeg = z * Ksub, kend = kbeg + Ksub;

  const int tid = threadIdx.x, wave = tid >> 6, lane = tid & 63;
  const int wm = (wave & 1) * 32, wn = (wave >> 1) * 64;

  floatx4 acc[2][4] = {};

  const int srow = tid >> 3;
  const int scol = ((tid & 7) ^ (srow & 7)) * 8;
  const __bf16* gA = A + (size_t)(m0 + srow) * K + scol;
  const __bf16* gB = W + (size_t)(n0 + srow) * K + scol;

  const int lm = lane & 15, lk = lane >> 4;
  const int g0 = ((lk    ) ^ (lane & 7)) * 8;
  const int g1 = ((lk + 4) ^ (lane & 7)) * 8;

  int buf = 0;
  {
    #pragma unroll
    for (int p = 0; p < 2; p++)
      gload_lds16(gA + (size_t)(p*32)*K + kbeg, sA[0] + p*2048 + tid*8);
    #pragma unroll
    for (int p = 0; p < 4; p++)
      gload_lds16(gB + (size_t)(p*32)*K + kbeg, sB[0] + p*2048 + tid*8);
  }

  for (int k0 = kbeg; k0 < kend; k0 += 64) {
    __syncthreads();
    if (k0 + 64 < kend) {
      const int nb = buf ^ 1;
      #pragma unroll
      for (int p = 0; p < 2; p++)
        gload_lds16(gA + (size_t)(p*32)*K + (k0+64), sA[nb] + p*2048 + tid*8);
      #pragma unroll
      for (int p = 0; p < 4; p++)
        gload_lds16(gB + (size_t)(p*32)*K + (k0+64), sB[nb] + p*2048 + tid*8);
    }
    const __bf16* pA = sA[buf] + (wm + lm) * 64;
    const __bf16* pB = sB[buf] + (wn + lm) * 64;
    bf16x8 a0[2], a1[2], b0[4], b1[4];
    #pragma unroll
    for (int i = 0; i < 2; i++) {
      a0[i] = *(const bf16x8*)(pA + i*1024 + g0);
      a1[i] = *(const bf16x8*)(pA + i*1024 + g1);
    }
    #pragma unroll
    for (int j = 0; j < 4; j++) {
      b0[j] = *(const bf16x8*)(pB + j*1024 + g0);
      b1[j] = *(const bf16x8*)(pB + j*1024 + g1);
    }
    #pragma unroll
    for (int i = 0; i < 2; i++)
      #pragma unroll
      for (int j = 0; j < 4; j++) {
        acc[i][j] = __builtin_amdgcn_mfma_f32_16x16x32_bf16(a0[i], b0[j], acc[i][j], 0, 0, 0);
        acc[i][j] = __builtin_amdgcn_mfma_f32_16x16x32_bf16(a1[i], b1[j], acc[i][j], 0, 0, 0);
      }
    buf ^= 1;
  }

  float* Cp = C + (size_t)z * pstride;
  const int en = n0 + wn + lm;
  const int em = m0 + wm + lk * 4;
  #pragma unroll
  for (int i = 0; i < 2; i++) {
    #pragma unroll
    for (int r = 0; r < 4; r++) {
      int m = em + i * 16 + r;
      if (m >= M) continue;
      #pragma unroll
      for (int j = 0; j < 4; j++)
        Cp[(size_t)m * N + en + j * 16] = acc[i][j][r];
    }
  }
}

// ---------------- split-K reduce for dt: +bias, softplus, transpose -> dvT ----
__global__ __launch_bounds__(256) void reduce_dt_k(const float* __restrict__ p0,
    const float* __restrict__ bias, float* __restrict__ dvT) {
  __shared__ float s[32 * 65];
  const float* p1 = p0 + (size_t)ROWS * D_INNER;
  const int b = blockIdx.x, d0 = blockIdx.y * 64, l0 = blockIdx.z * 32;
  const int t = threadIdx.x;
  #pragma unroll
  for (int e = 0; e < 8; e++) {
    int idx = e * 256 + t;
    int d = idx & 63, l = idx >> 6;
    float v = 0.f;
    int gl = l0 + l;
    if (gl < LSEQ) {
      size_t row = (size_t)(b * LSEQ + gl) * D_INNER + d0 + d;
      v = p0[row] + p1[row] + bias[d0 + d];
      v = (v > 20.f) ? v : log1pf(__expf(v));
    }
    s[l * 65 + d] = v;
  }
  __syncthreads();
  #pragma unroll
  for (int e = 0; e < 8; e++) {
    int idx = e * 256 + t;
    int ll = idx & 31, dd = idx >> 5;
    int gl = l0 + ll;
    if (gl < LP)
      dvT[((size_t)b * D_INNER + d0 + dd) * LP + gl] = s[ll * 65 + dd];
  }
}

// ---------------- fused depthwise conv1d + silu + gate-prep ----------------
__global__ __launch_bounds__(256) void convf_k(const float* __restrict__ xz,
    const float* __restrict__ cw, const float* __restrict__ cb,
    const float* __restrict__ Dp, __bf16* __restrict__ xc_b,
    float* __restrict__ xvT, float* __restrict__ gmT, float* __restrict__ gaT) {
  const int b = blockIdx.x, dc = blockIdx.y, lc = blockIdx.z * 52;
  const int d = dc * 256 + threadIdx.x;
  const int lend = min(lc + 52, LSEQ);
  const float* w = cw + (size_t)d * 4;
  const float w0 = w[0], w1 = w[1], w2 = w[2], w3 = w[3];
  const float bias = cb[d], dp = Dp[d];
  float xm3 = 0.f, xm2 = 0.f, xm1 = 0.f;
  const size_t rowbase = ((size_t)b * LSEQ) * 3072 + d;
  if (lc >= 3) {
    xm3 = xz[rowbase + (size_t)(lc-3)*3072];
    xm2 = xz[rowbase + (size_t)(lc-2)*3072];
    xm1 = xz[rowbase + (size_t)(lc-1)*3072];
  }
  const size_t ch = (size_t)b * D_INNER + d;
  float* pxv = xvT + ch * LP;
  float* pgm = gmT + ch * LP;
  float* pga = gaT + ch * LP;

  int l = lc;
  for (; l + 3 < lend; l += 4) {
    float4 bxv, bgm, bga;
    #pragma unroll
    for (int q = 0; q < 4; q++) {
      int lq = l + q;
      float x0 = xz[rowbase + (size_t)lq*3072];
      float zc = xz[rowbase + (size_t)lq*3072 + 1536];
      float c = w0*xm3 + w1*xm2 + w2*xm1 + w3*x0 + bias;
      xm3 = xm2; xm2 = xm1; xm1 = x0;
      float xc = siluf(c);
      float gm = siluf(zc);
      (&bxv.x)[q] = xc; (&bgm.x)[q] = gm; (&bga.x)[q] = dp*xc*gm;
      xc_b[((size_t)b*LSEQ + lq)*D_INNER + d] = (__bf16)xc;
    }
    *(float4*)(pxv + l) = bxv;
    *(float4*)(pgm + l) = bgm;
    *(float4*)(pga + l) = bga;
  }
  for (; l < lend; l++) {
    float x0 = xz[rowbase + (size_t)l*3072];
    float zc = xz[rowbase + (size_t)l*3072 + 1536];
    float c = w0*xm3 + w1*xm2 + w2*xm1 + w3*x0 + bias;
    xm3 = xm2; xm2 = xm1; xm1 = x0;
    float xc = siluf(c);
    float gm = siluf(zc);
    xc_b[((size_t)b*LSEQ + l)*D_INNER + d] = (__bf16)xc;
    pxv[l] = xc; pgm[l] = gm; pga[l] = dp*xc*gm;
  }
}

// ---------------- x_proj -> transposed BsT[(b*16+n)*LP + l] ----------------
__global__ void xproj_k(const __bf16* __restrict__ xc, const float* __restrict__ xpw,
                        float* __restrict__ BsT) {
  int row = blockIdx.x;
  int b = row / LSEQ, l = row - b * LSEQ;
  int n = threadIdx.x & 15, stripe = threadIdx.x >> 4;
  const __bf16* xr = xc + (size_t)row * D_INNER;
  const float* wr = xpw + (size_t)n * D_INNER;
  float s = 0.f;
  int k0 = stripe * 96;
  for (int k = k0; k < k0 + 96; k++) s += (float)xr[k] * wr[k];
  __shared__ float red[16][17];
  red[stripe][n] = s;
  __syncthreads();
  if (threadIdx.x < 16) {
    float t = 0.f;
    #pragma unroll
    for (int i = 0; i < 16; i++) t += red[i][threadIdx.x];
    BsT[((size_t)b*16 + threadIdx.x)*LP + l] = t;
  }
}

// ---------------- selective scan: register-chunk + DPP butterfly ----------------
__global__ __launch_bounds__(256) void scan3_k(const float* __restrict__ dvT,
    const float* __restrict__ xvT, const float* __restrict__ gmT,
    const float* __restrict__ gaT, const float* __restrict__ BsT,
    const float* __restrict__ A_log, __bf16* __restrict__ y) {
  const int grp = threadIdx.x >> 4, n = threadIdx.x & 15;
  const int ch = blockIdx.x * 16 + grp;
  const int b = ch / D_INNER, d = ch - b * D_INNER;
  const float a = -__expf(A_log[(size_t)d * 16 + n]);
  const size_t base = (size_t)ch * LP;
  const size_t bnb  = ((size_t)b * 16 + n) * LP;
  const size_t brow = (size_t)b * LSEQ;
  float s = 0.f;
  for (int l0 = 0; l0 < LP; l0 += 16) {
    float dv[16], xv[16], bn[16];
    #pragma unroll
    for (int q = 0; q < 4; q++) {
      *(float4*)(dv + q*4) = *(const float4*)(dvT + base + l0 + q*4);
      *(float4*)(xv + q*4) = *(const float4*)(xvT + base + l0 + q*4);
      *(float4*)(bn + q*4) = *(const float4*)(BsT + bnb  + l0 + q*4);
    }
    float gm = gmT[base + l0 + n];
    float ga = gaT[base + l0 + n];
    float yreg = 0.f;
    #pragma unroll
    for (int j = 0; j < 16; j++) {
      s = __expf(dv[j] * a) * s + (dv[j] * xv[j]) * bn[j];
      float part = s * bn[j];
      part = dpp_addf<0xB1>(part);    // xor 1
      part = dpp_addf<0x4E>(part);    // xor 2
      part = dpp_addf<0x141>(part);   // xor 7 (row_half_mirror)
      part = dpp_addf<0x140>(part);   // xor 15 (row_mirror)
      yreg = (n == j) ? part : yreg;
    }
    int lo = l0 + n;
    if (lo < LSEQ) y[(brow + lo) * D_INNER + d] = (__bf16)(yreg * gm + ga);
  }
}

extern "C" void kernel_launch(void* const* d_in, const int* in_sizes, int n_in,
                              void* d_out, int out_size, void* d_ws, size_t ws_size,
                              hipStream_t stream) {
  const float* x         = (const float*)d_in[0];
  const float* conv_w    = (const float*)d_in[1];
  const float* conv_b    = (const float*)d_in[2];
  const float* cls_token = (const float*)d_in[3];
  const float* pos_embed = (const float*)d_in[4];
  const float* ln_w      = (const float*)d_in[5];
  const float* ln_b      = (const float*)d_in[6];
  const float* in_proj_w = (const float*)d_in[7];
  const float* conv1d_w  = (const float*)d_in[8];
  const float* conv1d_b  = (const float*)d_in[9];
  const float* x_proj_w  = (const float*)d_in[10];
  const float* dt_proj_w = (const float*)d_in[11];
  const float* dt_proj_b = (const float*)d_in[12];
  const float* A_log     = (const float*)d_in[13];
  const float* D_param   = (const float*)d_in[14];
  const float* out_proj_w= (const float*)d_in[15];
  const float* norm_w    = (const float*)d_in[16];
  const float* norm_b    = (const float*)d_in[17];

  const int N_IN  = 2*D_INNER*D_MODEL;   // 2359296
  const int N_DT  = D_INNER*D_INNER;     // 2359296
  const int N_OUT = D_MODEL*D_INNER;     // 1179648
  const size_t TSZ = (size_t)BATCH * D_INNER * LP * 4;

  char* wsb = (char*)d_ws;
  size_t off = 0;
  float* t     = (float*)(wsb + off); off += (size_t)ROWS*768*4;
  float* xz    = (float*)(wsb + off); off += (size_t)ROWS*3072*4;  // also split-K partials
  float* BsT   = (float*)(wsb + off); off += (size_t)BATCH*16*LP*4;
  float* dvT   = (float*)(wsb + off); off += TSZ;
  float* xvT   = (float*)(wsb + off); off += TSZ;
  float* gmT   = (float*)(wsb + off); off += TSZ;
  float* gaT   = (float*)(wsb + off); off += TSZ;
  __bf16* xn_b = (__bf16*)(wsb + off); off += (size_t)MPAD*768*2;
  __bf16* xc_b = (__bf16*)(wsb + off); off += (size_t)MPAD*1536*2;
  __bf16* y_b  = (__bf16*)(wsb + off); off += (size_t)MPAD*1536*2;
  __bf16* col_b= (__bf16*)(wsb + off); off += (size_t)MPAD*768*2;
  __bf16* cw_b = (__bf16*)(wsb + off); off += (size_t)768*768*2;
  __bf16* wb_in  = (__bf16*)(wsb + off); off += (size_t)DEPTH*N_IN*2;
  __bf16* wb_dt  = (__bf16*)(wsb + off); off += (size_t)DEPTH*N_DT*2;
  __bf16* wb_out = (__bf16*)(wsb + off); off += (size_t)DEPTH*N_OUT*2;

  float* part = xz;  // xz is free after convf; dt partials consumed before out partials

  // ---- upfront: all weight conversions (4 dispatches, full-BW) ----
  cvt_k<<<(768*768/4 + 255)/256, 256, 0, stream>>>(conv_w, cw_b, 768*768);
  cvt_k<<<(DEPTH*N_IN/4 + 255)/256, 256, 0, stream>>>(in_proj_w, wb_in, DEPTH*N_IN);
  cvt_k<<<(DEPTH*N_DT/4 + 255)/256, 256, 0, stream>>>(dt_proj_w, wb_dt, DEPTH*N_DT);
  cvt_k<<<(DEPTH*N_OUT/4 + 255)/256, 256, 0, stream>>>(out_proj_w, wb_out, DEPTH*N_OUT);

  // ---- patch embed as bf16 MFMA GEMM ----
  float* P = xz;  // reuse
  im2col_k<<<(PROWS*768 + 255)/256, 256, 0, stream>>>(x, col_b);
  mgemm3_k<<<25*6, 256, 0, stream>>>(col_b, cw_b, P, 0, PROWS, 768, 768, 768, 6, 6);
  assemble_k<<<ROWS, 256, 0, stream>>>(P, conv_b, cls_token, pos_embed, t);

  // layer 0 LN (no fused residual)
  lnf_k<__bf16,0><<<ROWS, 256, 0, stream>>>(t, nullptr, ln_w, ln_b, xn_b);

  for (int i = 0; i < DEPTH; i++) {
    // in_proj: N=3072 (nt=24), no split-K -> combos 24
    mgemm3_k<<<25*24, 256, 0, stream>>>(xn_b, wb_in + (size_t)i*N_IN, xz, 0,
                                        ROWS, 3072, 768, 768, 24, 24);
    convf_k<<<dim3(8, 6, 4), 256, 0, stream>>>(xz, conv1d_w + (size_t)i*D_INNER*4,
        conv1d_b + (size_t)i*D_INNER, D_param + (size_t)i*D_INNER,
        xc_b, xvT, gmT, gaT);
    xproj_k<<<ROWS, 256, 0, stream>>>(xc_b, x_proj_w + (size_t)i*32*D_INNER + 16*D_INNER, BsT);
    // dt_proj: N=1536 (nt=12), split-K x2 -> combos 24
    mgemm3_k<<<25*24, 256, 0, stream>>>(xc_b, wb_dt + (size_t)i*N_DT, part,
        (size_t)ROWS*D_INNER, ROWS, 1536, 1536, 768, 24, 12);
    reduce_dt_k<<<dim3(8, 24, 7), 256, 0, stream>>>(part,
        dt_proj_b + (size_t)i*D_INNER, dvT);
    scan3_k<<<(BATCH*D_INNER)/16, 256, 0, stream>>>(dvT, xvT, gmT, gaT, BsT,
        A_log + (size_t)i*D_INNER*D_STATE, y_b);
    // out_proj: N=768 (nt=6), split-K x4 -> combos 24
    mgemm3_k<<<25*24, 256, 0, stream>>>(y_b, wb_out + (size_t)i*N_OUT, part,
        (size_t)ROWS*768, ROWS, 768, 1536, 384, 24, 6);
    // fused: t += sum(partials); LN -> next xn_b (or final LN -> d_out)
    if (i < DEPTH-1)
      lnf_k<__bf16,1><<<ROWS, 256, 0, stream>>>(t, part,
          ln_w + (size_t)(i+1)*768, ln_b + (size_t)(i+1)*768, xn_b);
    else
      lnf_k<float,2><<<ROWS, 256, 0, stream>>>(t, part, norm_w, norm_b, (float*)d_out);
  }
}